// Round 10
// baseline (277.680 us; speedup 1.0000x reference)
//
#include <hip/hip_runtime.h>
#include <hip/hip_bf16.h>
#include <math.h>

#define BB 2
#define SS 2048
#define DD 1024
#define HH 16
#define DKK 64
#define BH (BB * HH)          // 32

typedef __bf16 bf16_t;
typedef _Float16 f16_t;
typedef __attribute__((ext_vector_type(8))) _Float16 f16x8;
typedef __attribute__((ext_vector_type(4))) _Float16 f16x4;
typedef __attribute__((ext_vector_type(4))) float f32x4;
typedef __attribute__((ext_vector_type(4))) int i32x4;
typedef __attribute__((ext_vector_type(2))) int i32x2;

// async global->LDS, 16B per lane; lds base must be wave-uniform (lane*16 implicit)
#define GLD_LDS(gp, lp) __builtin_amdgcn_global_load_lds( \
    (const __attribute__((address_space(1))) void*)(gp),  \
    (__attribute__((address_space(3))) void*)(lp), 16, 0, 0)

static __device__ __forceinline__ int pkrtz(float a, float b) {
    auto h = __builtin_amdgcn_cvt_pkrtz(a, b);  // __fp16 ext_vector(2) on this clang
    return __builtin_bit_cast(int, h);
}

// ---------------------------------------------------------------- merged prep kernel
// One launch: x->fp16, [Wq;Wk]->hi/lo fp16, Wv/Wo->fp16, mask flags.
__global__ void prep_all(const float* __restrict__ x, const int* __restrict__ mask,
                         const float* __restrict__ Wq, const float* __restrict__ Wk,
                         const float* __restrict__ Wv, const float* __restrict__ Wo,
                         f16_t* __restrict__ xf,
                         f16_t* __restrict__ wqkh, f16_t* __restrict__ wqkl,
                         f16_t* __restrict__ wvf, f16_t* __restrict__ wof,
                         int* __restrict__ flags) {
    const int NXi = BB * SS * DD;   // 4194304
    const int NWi = DD * DD;        // 1048576
    const int total = NXi + 4 * NWi;
    int i = blockIdx.x * blockDim.x + threadIdx.x;
    const int stride = gridDim.x * blockDim.x;
    for (; i < total; i += stride) {
        if (i < NXi) {
            xf[i] = (f16_t)x[i];
        } else if (i < NXi + 2 * NWi) {
            const int j = i - NXi;
            const float v = (j < NWi) ? Wq[j] : Wk[j - NWi];
            const f16_t h = (f16_t)v;
            wqkh[j] = h;
            wqkl[j] = (f16_t)(v - (float)h);
        } else {
            const int j = i - NXi - 2 * NWi;
            if (j < NWi) wvf[j] = (f16_t)Wv[j];
            else         wof[j - NWi] = (f16_t)Wo[j - NWi];
        }
    }
    if (blockIdx.x == 0 && threadIdx.x < BB * (SS / 128)) {
        const int f = threadIdx.x;
        const int b = f / (SS / 128), t = f % (SS / 128);
        const int* p = mask + b * SS + t * 128;
        int all = 1;
        for (int j = 0; j < 128; ++j) all &= (p[j] != 0);
        flags[f] = all;
    }
}

// ---------------------------------------------------------------- fused QKV GEMM (fp16)
__global__ __launch_bounds__(256) void gemm_qkv(const f16_t* __restrict__ Af,
                                                const f16_t* __restrict__ Wqkh,
                                                const f16_t* __restrict__ Wqkl,
                                                const f16_t* __restrict__ Wvf,
                                                const float* __restrict__ bq,
                                                const float* __restrict__ bk,
                                                const float* __restrict__ bv,
                                                f16_t* __restrict__ q_o,
                                                f16_t* __restrict__ k_o,
                                                f16_t* __restrict__ vt_o,
                                                int K) {
    __shared__ __align__(16) f16_t sA[4096];
    __shared__ __align__(16) f16_t sB0[4096];
    __shared__ __align__(16) f16_t sB1[4096];

    const int tid  = threadIdx.x;
    const int wv   = tid >> 6;
    const int lane = tid & 63;
    const int quad = lane >> 4;
    const int l15  = lane & 15;
    const int wr   = wv >> 1;
    const int wc   = wv & 1;
    const int row0 = blockIdx.y * 128;
    const int col0 = blockIdx.x * 128;
    const bool isV = (col0 >= 2048);

    const f16_t* B0 = isV ? (Wvf + (long)(col0 - 2048) * K) : (Wqkh + (long)col0 * K);
    const f16_t* B1 = isV ? nullptr : (Wqkl + (long)col0 * K);

    f32x4 acc[4][4] = {};

    const int srow = tid >> 2;
    const int scol = (tid & 3) * 8;
    const long aoff = (long)(row0 + srow) * K + scol;
    const long boff = (long)srow * K + scol;

    if (isV) {
#pragma unroll 1
        for (int kb = 0; kb < K; kb += 32) {
#pragma unroll
            for (int p = 0; p < 2; ++p) {
                const long go = (long)p * 64 * K + kb;
                const int lo = p * 2048 + wv * 512;
                GLD_LDS(Af + aoff + go, sA + lo);
                GLD_LDS(B0 + boff + go, sB0 + lo);
            }
            __syncthreads();
            f16x8 af[4];
#pragma unroll
            for (int mt = 0; mt < 4; ++mt)
                af[mt] = *(const f16x8*)&sA[(wr * 64 + mt * 16 + l15) * 32 + quad * 8];
#pragma unroll
            for (int nt = 0; nt < 4; ++nt) {
                f16x8 b0 = *(const f16x8*)&sB0[(wc * 64 + nt * 16 + l15) * 32 + quad * 8];
#pragma unroll
                for (int mt = 0; mt < 4; ++mt)
                    acc[mt][nt] = __builtin_amdgcn_mfma_f32_16x16x32_f16(af[mt], b0, acc[mt][nt], 0, 0, 0);
            }
            __syncthreads();
        }
    } else {
#pragma unroll 1
        for (int kb = 0; kb < K; kb += 32) {
#pragma unroll
            for (int p = 0; p < 2; ++p) {
                const long go = (long)p * 64 * K + kb;
                const int lo = p * 2048 + wv * 512;
                GLD_LDS(Af + aoff + go, sA + lo);
                GLD_LDS(B0 + boff + go, sB0 + lo);
                GLD_LDS(B1 + boff + go, sB1 + lo);
            }
            __syncthreads();
            f16x8 af[4];
#pragma unroll
            for (int mt = 0; mt < 4; ++mt)
                af[mt] = *(const f16x8*)&sA[(wr * 64 + mt * 16 + l15) * 32 + quad * 8];
#pragma unroll
            for (int nt = 0; nt < 4; ++nt) {
                f16x8 b0 = *(const f16x8*)&sB0[(wc * 64 + nt * 16 + l15) * 32 + quad * 8];
                f16x8 b1 = *(const f16x8*)&sB1[(wc * 64 + nt * 16 + l15) * 32 + quad * 8];
#pragma unroll
                for (int mt = 0; mt < 4; ++mt) {
                    acc[mt][nt] = __builtin_amdgcn_mfma_f32_16x16x32_f16(af[mt], b0, acc[mt][nt], 0, 0, 0);
                    acc[mt][nt] = __builtin_amdgcn_mfma_f32_16x16x32_f16(af[mt], b1, acc[mt][nt], 0, 0, 0);
                }
            }
            __syncthreads();
        }
    }

    if (isV) {
#pragma unroll
        for (int nt = 0; nt < 4; ++nt) {
            const int colv = (col0 - 2048) + wc * 64 + nt * 16 + l15;  // [0,1024)
            const float bvv = bv[colv];
            const int hq = colv >> 6, dk = colv & 63;
#pragma unroll
            for (int mt = 0; mt < 4; ++mt) {
                const int grow0 = row0 + wr * 64 + mt * 16 + quad * 4;
                const int bq2 = grow0 >> 11;
                const int s0  = grow0 & (SS - 1);
                f16x4 pk;
#pragma unroll
                for (int r = 0; r < 4; ++r) pk[r] = (f16_t)(acc[mt][nt][r] + bvv);
                *(f16x4*)(vt_o + ((long)(bq2 * HH + hq) * DKK + dk) * SS + s0) = pk;
            }
        }
    } else {
        const bool isK = (col0 >= 1024);
        const float* bias = isK ? bk : bq;
        f16_t* op = isK ? k_o : q_o;
#pragma unroll
        for (int nt = 0; nt < 4; ++nt) {
            const int gcol = (col0 & 1023) + wc * 64 + nt * 16 + l15;
            const float bvv = bias[gcol];
            const int hq = gcol >> 6, dk = gcol & 63;
#pragma unroll
            for (int mt = 0; mt < 4; ++mt) {
                const int grow0 = row0 + wr * 64 + mt * 16 + quad * 4;
#pragma unroll
                for (int r = 0; r < 4; ++r) {
                    int grow = grow0 + r;
                    float vvv = acc[mt][nt][r] + bvv;
                    long off = (((long)(grow >> 11) * HH + hq) * SS + (grow & (SS - 1))) * DKK + dk;
                    op[off] = (f16_t)vvv;
                }
            }
        }
    }
}

// ---------------------------------------------------------------- O-projection GEMM (fp16 in, fp32 out)
// Tile 64x128, BK=32 (round-6 version: 512 blocks, best measured total).
__global__ __launch_bounds__(256) void gemm_o(const f16_t* __restrict__ Ah,
                                              const f16_t* __restrict__ Bhp,
                                              const float* __restrict__ bias,
                                              float* __restrict__ outf,
                                              int N, int K) {
    __shared__ __align__(16) f16_t lds[2048 + 4096];
    f16_t* Ash = lds;
    f16_t* Bsh = lds + 2048;

    const int tid  = threadIdx.x;
    const int wv   = tid >> 6;
    const int lane = tid & 63;
    const int quad = lane >> 4;
    const int l15  = lane & 15;
    const int wr   = wv >> 1;
    const int wc   = wv & 1;
    const int row0 = blockIdx.y * 64;
    const int col0 = blockIdx.x * 128;

    f32x4 acc[2][4] = {};

    const int srow = lane >> 2;
    const int scol = (lane & 3) * 8;
    const f16_t* gA  = Ah  + (long)(row0 + wv * 16 + srow) * K + scol;
    const f16_t* gB0 = Bhp + (long)(col0 + wv * 16 + srow) * K + scol;
    const f16_t* gB1 = Bhp + (long)(col0 + (wv + 4) * 16 + srow) * K + scol;
    f16_t* lA  = Ash + wv * 512;
    f16_t* lB0 = Bsh + wv * 512;
    f16_t* lB1 = Bsh + (wv + 4) * 512;

#pragma unroll 1
    for (int kb = 0; kb < K; kb += 32) {
        GLD_LDS(gA + kb, lA);
        GLD_LDS(gB0 + kb, lB0);
        GLD_LDS(gB1 + kb, lB1);
        __syncthreads();

        f16x8 af[2];
#pragma unroll
        for (int mt = 0; mt < 2; ++mt)
            af[mt] = *(const f16x8*)&Ash[(wr * 32 + mt * 16 + l15) * 32 + quad * 8];
#pragma unroll
        for (int nt = 0; nt < 4; ++nt) {
            f16x8 bh = *(const f16x8*)&Bsh[(wc * 64 + nt * 16 + l15) * 32 + quad * 8];
#pragma unroll
            for (int mt = 0; mt < 2; ++mt)
                acc[mt][nt] = __builtin_amdgcn_mfma_f32_16x16x32_f16(af[mt], bh, acc[mt][nt], 0, 0, 0);
        }
        __syncthreads();
    }

#pragma unroll
    for (int mt = 0; mt < 2; ++mt) {
#pragma unroll
        for (int nt = 0; nt < 4; ++nt) {
            const int gcol  = col0 + wc * 64 + nt * 16 + l15;
            const float bvv = bias[gcol];
            const int grow0 = row0 + wr * 32 + mt * 16 + quad * 4;
#pragma unroll
            for (int r = 0; r < 4; ++r)
                outf[(long)(grow0 + r) * N + gcol] = acc[mt][nt][r] + bvv;
        }
    }
}

// ---------------------------------------------------------------- MFMA flash attention v11
// (unchanged: best attn = 88.9us)
__global__ __launch_bounds__(256, 3) void attn_mfma11(const f16_t* __restrict__ Qp,
                                                      const f16_t* __restrict__ Kp,
                                                      const f16_t* __restrict__ Vtp,
                                                      const int* __restrict__ mask,
                                                      const int* __restrict__ flags,
                                                      f16_t* __restrict__ ctx,
                                                      int seq_len) {
    __shared__ __align__(16) f16_t Ksh[2][4096];      // single K tile, [64-key sub-tile][...]
    __shared__ __align__(16) f16_t Vsh[2][2][4096];   // dbuf V^T: [buf][sub-tile][d][key]

    const int tid  = threadIdx.x;
    const int wv   = tid >> 6;
    const int lane = tid & 63;
    const int quad = lane >> 4;
    const int l15  = lane & 15;
    const int bh   = blockIdx.y;
    const int b    = bh >> 4;
    const int h    = bh & 15;
    const int q0   = blockIdx.x * 128 + wv * 16;   // group 0 rows; group 1 = +64

    const long kb = (long)bh * SS * DKK;

    f16x8 qf0[2], qf1[2];
    {
        const f16_t* pq = Qp + kb + (long)(q0 + l15) * DKK + quad * 8;
        qf0[0] = *(const f16x8*)pq;
        qf0[1] = *(const f16x8*)(pq + 32);
        const f16_t* pq1 = pq + 64 * DKK;
        qf1[0] = *(const f16x8*)pq1;
        qf1[1] = *(const f16x8*)(pq1 + 32);
        const f16_t qs = (f16_t)(8.0f * 1.44269504088896f);
#pragma unroll
        for (int j = 0; j < 8; ++j) {
            qf0[0][j] *= qs; qf0[1][j] *= qs;
            qf1[0][j] *= qs; qf1[1][j] *= qs;
        }
    }

    f16x4 ones4;
#pragma unroll
    for (int j = 0; j < 4; ++j) ones4[j] = (f16_t)1.0f;

    f32x4 o0[4], o1[4], lacc0, lacc1;
#pragma unroll
    for (int r = 0; r < 4; ++r) {
        o0[r] = (f32x4){0.f, 0.f, 0.f, 0.f};
        o1[r] = (f32x4){0.f, 0.f, 0.f, 0.f};
    }
    lacc0 = (f32x4){0.f, 0.f, 0.f, 0.f};
    lacc1 = (f32x4){0.f, 0.f, 0.f, 0.f};
    float m0 = -1e30f, m1 = -1e30f;   // running max for q = l15 (per group)

    const int* mrow = mask + b * SS;
    const int* frow = flags + b * (SS / 128);

    const int srow8 = lane >> 3;
    const int gcolB = ((lane & 7) ^ srow8) * 8;
    const int NT = seq_len >> 7;

    // prologue: stage K(0) -> Ksh, V(0) -> Vsh[0]
#pragma unroll
    for (int c = 0; c < 2; ++c) {
#pragma unroll
        for (int p = 0; p < 2; ++p) {
            const int i = wv * 2 + p;
            const int row = i * 8 + srow8;
            GLD_LDS(Kp + kb + (long)(c * 64 + row) * DKK + gcolB, &Ksh[c][i * 512]);
            GLD_LDS(Vtp + kb + (long)row * SS + c * 64 + gcolB, &Vsh[0][c][i * 512]);
        }
    }

#pragma unroll 1
    for (int tt = 0; tt < NT; ++tt) {
        const int cur = tt & 1;
        const int kt = tt << 7;
        __syncthreads();   // B_top: K(tt) and V(tt)=Vsh[cur] staged (vmcnt drained)

        // QK^T swapped, shared K-fragments feed both q-groups
        f32x4 s0[8], s1[8];
#pragma unroll
        for (int nt = 0; nt < 8; ++nt) {
            s0[nt] = (f32x4){0.f, 0.f, 0.f, 0.f};
            s1[nt] = (f32x4){0.f, 0.f, 0.f, 0.f};
        }
#pragma unroll
        for (int nt = 0; nt < 8; ++nt) {
            const int c = nt >> 2;
            const int kr = (nt & 3) * 16 + l15;
#pragma unroll
            for (int dt = 0; dt < 2; ++dt) {
                f16x8 kf = *(const f16x8*)&Ksh[c][kr * 64 + (((dt * 4 + quad) ^ (l15 & 7)) << 3)];
                s0[nt] = __builtin_amdgcn_mfma_f32_16x16x32_f16(kf, qf0[dt], s0[nt], 0, 0, 0);
                s1[nt] = __builtin_amdgcn_mfma_f32_16x16x32_f16(kf, qf1[dt], s1[nt], 0, 0, 0);
            }
        }

        __syncthreads();   // B_mid: all waves done reading Ksh -> safe to restage
        if (tt + 1 < NT) {
            const int kn = (tt + 1) << 7;
#pragma unroll
            for (int c = 0; c < 2; ++c) {
#pragma unroll
                for (int p = 0; p < 2; ++p) {
                    const int i = wv * 2 + p;
                    const int row = i * 8 + srow8;
                    GLD_LDS(Kp + kb + (long)(kn + c * 64 + row) * DKK + gcolB, &Ksh[c][i * 512]);
                    GLD_LDS(Vtp + kb + (long)row * SS + kn + c * 64 + gcolB, &Vsh[cur ^ 1][c][i * 512]);
                }
            }
        }

        if (!frow[kt >> 7]) {
#pragma unroll
            for (int nt = 0; nt < 8; ++nt) {
                i32x4 kp = *(const i32x4*)&mrow[kt + nt * 16 + quad * 4];
#pragma unroll
                for (int r = 0; r < 4; ++r) {
                    s0[nt][r] = kp[r] ? s0[nt][r] : -1e30f;
                    s1[nt][r] = kp[r] ? s1[nt][r] : -1e30f;
                }
            }
        }

        // per-group max over this q-row's keys (independent chains)
        f32x4 mxa, mxb;
#pragma unroll
        for (int r = 0; r < 4; ++r) {
            mxa[r] = fmaxf(fmaxf(fmaxf(s0[0][r], s0[1][r]), fmaxf(s0[2][r], s0[3][r])),
                           fmaxf(fmaxf(s0[4][r], s0[5][r]), fmaxf(s0[6][r], s0[7][r])));
            mxb[r] = fmaxf(fmaxf(fmaxf(s1[0][r], s1[1][r]), fmaxf(s1[2][r], s1[3][r])),
                           fmaxf(fmaxf(s1[4][r], s1[5][r]), fmaxf(s1[6][r], s1[7][r])));
        }
        float tm0 = fmaxf(fmaxf(mxa[0], mxa[1]), fmaxf(mxa[2], mxa[3]));
        float tm1 = fmaxf(fmaxf(mxb[0], mxb[1]), fmaxf(mxb[2], mxb[3]));
        tm0 = fmaxf(tm0, __shfl_xor(tm0, 16));
        tm1 = fmaxf(tm1, __shfl_xor(tm1, 16));
        tm0 = fmaxf(tm0, __shfl_xor(tm0, 32));
        tm1 = fmaxf(tm1, __shfl_xor(tm1, 32));

        const float mn0 = fmaxf(m0, tm0);
        const float mn1 = fmaxf(m1, tm1);
        if (__any(tm0 > m0)) {
            const float alpha = exp2f(m0 - mn0);
            float a4[4];
#pragma unroll
            for (int r = 0; r < 4; ++r) a4[r] = __shfl(alpha, quad * 4 + r);
#pragma unroll
            for (int t = 0; t < 4; ++t)
#pragma unroll
                for (int r = 0; r < 4; ++r) o0[t][r] *= a4[r];
#pragma unroll
            for (int r = 0; r < 4; ++r) lacc0[r] *= a4[r];
        }
        if (__any(tm1 > m1)) {
            const float alpha = exp2f(m1 - mn1);
            float a4[4];
#pragma unroll
            for (int r = 0; r < 4; ++r) a4[r] = __shfl(alpha, quad * 4 + r);
#pragma unroll
            for (int t = 0; t < 4; ++t)
#pragma unroll
                for (int r = 0; r < 4; ++r) o1[t][r] *= a4[r];
#pragma unroll
            for (int r = 0; r < 4; ++r) lacc1[r] *= a4[r];
        }
        m0 = mn0;
        m1 = mn1;

        // per 16-key group: exp -> pack -> PV MFMA; vB read once, used by both groups
#pragma unroll
        for (int nt = 0; nt < 8; ++nt) {
            const int c = nt >> 2;
            i32x2 pp0, pp1;
            pp0[0] = pkrtz(exp2f(s0[nt][0] - mn0), exp2f(s0[nt][1] - mn0));
            pp0[1] = pkrtz(exp2f(s0[nt][2] - mn0), exp2f(s0[nt][3] - mn0));
            pp1[0] = pkrtz(exp2f(s1[nt][0] - mn1), exp2f(s1[nt][1] - mn1));
            pp1[1] = pkrtz(exp2f(s1[nt][2] - mn1), exp2f(s1[nt][3] - mn1));
            f16x4 paf0 = __builtin_bit_cast(f16x4, pp0);
            f16x4 paf1 = __builtin_bit_cast(f16x4, pp1);
            lacc0 = __builtin_amdgcn_mfma_f32_16x16x16f16(paf0, ones4, lacc0, 0, 0, 0);
            lacc1 = __builtin_amdgcn_mfma_f32_16x16x16f16(paf1, ones4, lacc1, 0, 0, 0);
            const int vcol = ((((nt & 3) * 2 + (quad >> 1)) ^ (l15 & 7)) << 3) + ((quad & 1) << 2);
#pragma unroll
            for (int t = 0; t < 4; ++t) {
                f16x4 vB = *(const f16x4*)&Vsh[cur][c][(t * 16 + l15) * 64 + vcol];
                o0[t] = __builtin_amdgcn_mfma_f32_16x16x16f16(paf0, vB, o0[t], 0, 0, 0);
                o1[t] = __builtin_amdgcn_mfma_f32_16x16x16f16(paf1, vB, o1[t], 0, 0, 0);
            }
        }
    }

    float inv0[4], inv1[4];
#pragma unroll
    for (int r = 0; r < 4; ++r) {
        inv0[r] = 1.0f / lacc0[r];
        inv1[r] = 1.0f / lacc1[r];
    }
#pragma unroll
    for (int t = 0; t < 4; ++t) {
        int d = t * 16 + l15;
#pragma unroll
        for (int r = 0; r < 4; ++r) {
            int tok = b * SS + q0 + quad * 4 + r;
            ctx[(long)tok * DD + h * DKK + d] = (f16_t)(o0[t][r] * inv0[r]);
            ctx[(long)(tok + 64) * DD + h * DKK + d] = (f16_t)(o1[t][r] * inv1[r]);
        }
    }
}

// ---------------------------------------------------------------- launch
extern "C" void kernel_launch(void* const* d_in, const int* in_sizes, int n_in,
                              void* d_out, int out_size, void* d_ws, size_t ws_size,
                              hipStream_t stream) {
    const float* x  = (const float*)d_in[0];
    const int* mask = (const int*)d_in[1];
    const float* Wq = (const float*)d_in[2];
    const float* bq = (const float*)d_in[3];
    const float* Wk = (const float*)d_in[4];
    const float* bk = (const float*)d_in[5];
    const float* Wv = (const float*)d_in[6];
    const float* bv = (const float*)d_in[7];
    const float* Wo = (const float*)d_in[8];
    const float* bo = (const float*)d_in[9];
    float* out = (float*)d_out;

    const long NX = (long)BB * SS * DD;  // 4194304
    const long NW = (long)DD * DD;       // 1048576

    char* ws = (char*)d_ws;
    f16_t* xf   = (f16_t*)ws; ws += NX * 2;
    f16_t* wqkh = (f16_t*)ws; ws += 2 * NW * 2;
    f16_t* wqkl = (f16_t*)ws; ws += 2 * NW * 2;
    f16_t* wvf  = (f16_t*)ws; ws += NW * 2;
    f16_t* wof  = (f16_t*)ws; ws += NW * 2;
    f16_t* qf   = (f16_t*)ws; ws += NX * 2;
    f16_t* kf   = (f16_t*)ws; ws += NX * 2;
    f16_t* vt   = (f16_t*)ws; ws += NX * 2;
    f16_t* ctx  = (f16_t*)ws; ws += NX * 2;
    int*   flg  = (int*)ws;   ws += 64 * 4;

    prep_all<<<2048, 256, 0, stream>>>(x, mask, Wq, Wk, Wv, Wo,
                                       xf, wqkh, wqkl, wvf, wof, flg);

    dim3 gqkv(3 * DD / 128, (BB * SS) / 128);  // (24, 32) = 768 blocks
    gemm_qkv<<<gqkv, 256, 0, stream>>>(xf, wqkh, wqkl, wvf, bq, bk, bv, qf, kf, vt, DD);

    dim3 agrid(SS / 128, BH);  // (16, 32) = 512 blocks, 128 q-rows each
    attn_mfma11<<<agrid, 256, 0, stream>>>(qf, kf, vt, mask, flg, ctx, SS);

    dim3 go(DD / 128, (BB * SS) / 64);  // (8, 64) = 512 blocks
    gemm_o<<<go, 256, 0, stream>>>(ctx, wof, bo, out, DD, DD);
}

// Round 11
// 262.852 us; speedup vs baseline: 1.0564x; 1.0564x over previous
//
#include <hip/hip_runtime.h>
#include <hip/hip_bf16.h>
#include <math.h>

#define BB 2
#define SS 2048
#define DD 1024
#define HH 16
#define DKK 64
#define BH (BB * HH)          // 32

typedef __bf16 bf16_t;
typedef _Float16 f16_t;
typedef __attribute__((ext_vector_type(8))) _Float16 f16x8;
typedef __attribute__((ext_vector_type(4))) _Float16 f16x4;
typedef __attribute__((ext_vector_type(4))) float f32x4;
typedef __attribute__((ext_vector_type(4))) int i32x4;
typedef __attribute__((ext_vector_type(2))) int i32x2;

// async global->LDS, 16B per lane; lds base must be wave-uniform (lane*16 implicit)
#define GLD_LDS(gp, lp) __builtin_amdgcn_global_load_lds( \
    (const __attribute__((address_space(1))) void*)(gp),  \
    (__attribute__((address_space(3))) void*)(lp), 16, 0, 0)

static __device__ __forceinline__ int pkrtz(float a, float b) {
    auto h = __builtin_amdgcn_cvt_pkrtz(a, b);  // __fp16 ext_vector(2) on this clang
    return __builtin_bit_cast(int, h);
}

// ---------------------------------------------------------------- merged prep kernel
__global__ void prep_all(const float* __restrict__ x, const int* __restrict__ mask,
                         const float* __restrict__ Wq, const float* __restrict__ Wk,
                         const float* __restrict__ Wv, const float* __restrict__ Wo,
                         f16_t* __restrict__ xf,
                         f16_t* __restrict__ wqkh, f16_t* __restrict__ wqkl,
                         f16_t* __restrict__ wvf, f16_t* __restrict__ wof,
                         int* __restrict__ flags) {
    const int NXi = BB * SS * DD;   // 4194304
    const int NWi = DD * DD;        // 1048576
    const int total = NXi + 4 * NWi;
    int i = blockIdx.x * blockDim.x + threadIdx.x;
    const int stride = gridDim.x * blockDim.x;
    for (; i < total; i += stride) {
        if (i < NXi) {
            xf[i] = (f16_t)x[i];
        } else if (i < NXi + 2 * NWi) {
            const int j = i - NXi;
            const float v = (j < NWi) ? Wq[j] : Wk[j - NWi];
            const f16_t h = (f16_t)v;
            wqkh[j] = h;
            wqkl[j] = (f16_t)(v - (float)h);
        } else {
            const int j = i - NXi - 2 * NWi;
            if (j < NWi) wvf[j] = (f16_t)Wv[j];
            else         wof[j - NWi] = (f16_t)Wo[j - NWi];
        }
    }
    if (blockIdx.x == 0 && threadIdx.x < BB * (SS / 128)) {
        const int f = threadIdx.x;
        const int b = f / (SS / 128), t = f % (SS / 128);
        const int* p = mask + b * SS + t * 128;
        int all = 1;
        for (int j = 0; j < 128; ++j) all &= (p[j] != 0);
        flags[f] = all;
    }
}

// ---------------------------------------------------------------- fused QKV GEMM (fp16)
__global__ __launch_bounds__(256) void gemm_qkv(const f16_t* __restrict__ Af,
                                                const f16_t* __restrict__ Wqkh,
                                                const f16_t* __restrict__ Wqkl,
                                                const f16_t* __restrict__ Wvf,
                                                const float* __restrict__ bq,
                                                const float* __restrict__ bk,
                                                const float* __restrict__ bv,
                                                f16_t* __restrict__ q_o,
                                                f16_t* __restrict__ k_o,
                                                f16_t* __restrict__ vt_o,
                                                int K) {
    __shared__ __align__(16) f16_t sA[4096];
    __shared__ __align__(16) f16_t sB0[4096];
    __shared__ __align__(16) f16_t sB1[4096];

    const int tid  = threadIdx.x;
    const int wv   = tid >> 6;
    const int lane = tid & 63;
    const int quad = lane >> 4;
    const int l15  = lane & 15;
    const int wr   = wv >> 1;
    const int wc   = wv & 1;
    const int row0 = blockIdx.y * 128;
    const int col0 = blockIdx.x * 128;
    const bool isV = (col0 >= 2048);

    const f16_t* B0 = isV ? (Wvf + (long)(col0 - 2048) * K) : (Wqkh + (long)col0 * K);
    const f16_t* B1 = isV ? nullptr : (Wqkl + (long)col0 * K);

    f32x4 acc[4][4] = {};

    const int srow = tid >> 2;
    const int scol = (tid & 3) * 8;
    const long aoff = (long)(row0 + srow) * K + scol;
    const long boff = (long)srow * K + scol;

    if (isV) {
#pragma unroll 1
        for (int kb = 0; kb < K; kb += 32) {
#pragma unroll
            for (int p = 0; p < 2; ++p) {
                const long go = (long)p * 64 * K + kb;
                const int lo = p * 2048 + wv * 512;
                GLD_LDS(Af + aoff + go, sA + lo);
                GLD_LDS(B0 + boff + go, sB0 + lo);
            }
            __syncthreads();
            f16x8 af[4];
#pragma unroll
            for (int mt = 0; mt < 4; ++mt)
                af[mt] = *(const f16x8*)&sA[(wr * 64 + mt * 16 + l15) * 32 + quad * 8];
#pragma unroll
            for (int nt = 0; nt < 4; ++nt) {
                f16x8 b0 = *(const f16x8*)&sB0[(wc * 64 + nt * 16 + l15) * 32 + quad * 8];
#pragma unroll
                for (int mt = 0; mt < 4; ++mt)
                    acc[mt][nt] = __builtin_amdgcn_mfma_f32_16x16x32_f16(af[mt], b0, acc[mt][nt], 0, 0, 0);
            }
            __syncthreads();
        }
    } else {
#pragma unroll 1
        for (int kb = 0; kb < K; kb += 32) {
#pragma unroll
            for (int p = 0; p < 2; ++p) {
                const long go = (long)p * 64 * K + kb;
                const int lo = p * 2048 + wv * 512;
                GLD_LDS(Af + aoff + go, sA + lo);
                GLD_LDS(B0 + boff + go, sB0 + lo);
                GLD_LDS(B1 + boff + go, sB1 + lo);
            }
            __syncthreads();
            f16x8 af[4];
#pragma unroll
            for (int mt = 0; mt < 4; ++mt)
                af[mt] = *(const f16x8*)&sA[(wr * 64 + mt * 16 + l15) * 32 + quad * 8];
#pragma unroll
            for (int nt = 0; nt < 4; ++nt) {
                f16x8 b0 = *(const f16x8*)&sB0[(wc * 64 + nt * 16 + l15) * 32 + quad * 8];
                f16x8 b1 = *(const f16x8*)&sB1[(wc * 64 + nt * 16 + l15) * 32 + quad * 8];
#pragma unroll
                for (int mt = 0; mt < 4; ++mt) {
                    acc[mt][nt] = __builtin_amdgcn_mfma_f32_16x16x32_f16(af[mt], b0, acc[mt][nt], 0, 0, 0);
                    acc[mt][nt] = __builtin_amdgcn_mfma_f32_16x16x32_f16(af[mt], b1, acc[mt][nt], 0, 0, 0);
                }
            }
            __syncthreads();
        }
    }

    if (isV) {
#pragma unroll
        for (int nt = 0; nt < 4; ++nt) {
            const int colv = (col0 - 2048) + wc * 64 + nt * 16 + l15;  // [0,1024)
            const float bvv = bv[colv];
            const int hq = colv >> 6, dk = colv & 63;
#pragma unroll
            for (int mt = 0; mt < 4; ++mt) {
                const int grow0 = row0 + wr * 64 + mt * 16 + quad * 4;
                const int bq2 = grow0 >> 11;
                const int s0  = grow0 & (SS - 1);
                f16x4 pk;
#pragma unroll
                for (int r = 0; r < 4; ++r) pk[r] = (f16_t)(acc[mt][nt][r] + bvv);
                *(f16x4*)(vt_o + ((long)(bq2 * HH + hq) * DKK + dk) * SS + s0) = pk;
            }
        }
    } else {
        const bool isK = (col0 >= 1024);
        const float* bias = isK ? bk : bq;
        f16_t* op = isK ? k_o : q_o;
#pragma unroll
        for (int nt = 0; nt < 4; ++nt) {
            const int gcol = (col0 & 1023) + wc * 64 + nt * 16 + l15;
            const float bvv = bias[gcol];
            const int hq = gcol >> 6, dk = gcol & 63;
#pragma unroll
            for (int mt = 0; mt < 4; ++mt) {
                const int grow0 = row0 + wr * 64 + mt * 16 + quad * 4;
#pragma unroll
                for (int r = 0; r < 4; ++r) {
                    int grow = grow0 + r;
                    float vvv = acc[mt][nt][r] + bvv;
                    long off = (((long)(grow >> 11) * HH + hq) * SS + (grow & (SS - 1))) * DKK + dk;
                    op[off] = (f16_t)vvv;
                }
            }
        }
    }
}

// ---------------------------------------------------------------- O-projection GEMM (fp16 in, fp32 out)
__global__ __launch_bounds__(256) void gemm_o(const f16_t* __restrict__ Ah,
                                              const f16_t* __restrict__ Bhp,
                                              const float* __restrict__ bias,
                                              float* __restrict__ outf,
                                              int N, int K) {
    __shared__ __align__(16) f16_t lds[2048 + 4096];
    f16_t* Ash = lds;
    f16_t* Bsh = lds + 2048;

    const int tid  = threadIdx.x;
    const int wv   = tid >> 6;
    const int lane = tid & 63;
    const int quad = lane >> 4;
    const int l15  = lane & 15;
    const int wr   = wv >> 1;
    const int wc   = wv & 1;
    const int row0 = blockIdx.y * 64;
    const int col0 = blockIdx.x * 128;

    f32x4 acc[2][4] = {};

    const int srow = lane >> 2;
    const int scol = (lane & 3) * 8;
    const f16_t* gA  = Ah  + (long)(row0 + wv * 16 + srow) * K + scol;
    const f16_t* gB0 = Bhp + (long)(col0 + wv * 16 + srow) * K + scol;
    const f16_t* gB1 = Bhp + (long)(col0 + (wv + 4) * 16 + srow) * K + scol;
    f16_t* lA  = Ash + wv * 512;
    f16_t* lB0 = Bsh + wv * 512;
    f16_t* lB1 = Bsh + (wv + 4) * 512;

#pragma unroll 1
    for (int kb = 0; kb < K; kb += 32) {
        GLD_LDS(gA + kb, lA);
        GLD_LDS(gB0 + kb, lB0);
        GLD_LDS(gB1 + kb, lB1);
        __syncthreads();

        f16x8 af[2];
#pragma unroll
        for (int mt = 0; mt < 2; ++mt)
            af[mt] = *(const f16x8*)&Ash[(wr * 32 + mt * 16 + l15) * 32 + quad * 8];
#pragma unroll
        for (int nt = 0; nt < 4; ++nt) {
            f16x8 bh = *(const f16x8*)&Bsh[(wc * 64 + nt * 16 + l15) * 32 + quad * 8];
#pragma unroll
            for (int mt = 0; mt < 2; ++mt)
                acc[mt][nt] = __builtin_amdgcn_mfma_f32_16x16x32_f16(af[mt], bh, acc[mt][nt], 0, 0, 0);
        }
        __syncthreads();
    }

#pragma unroll
    for (int mt = 0; mt < 2; ++mt) {
#pragma unroll
        for (int nt = 0; nt < 4; ++nt) {
            const int gcol  = col0 + wc * 64 + nt * 16 + l15;
            const float bvv = bias[gcol];
            const int grow0 = row0 + wr * 32 + mt * 16 + quad * 4;
#pragma unroll
            for (int r = 0; r < 4; ++r)
                outf[(long)(grow0 + r) * N + gcol] = acc[mt][nt][r] + bvv;
        }
    }
}

// ---------------------------------------------------------------- MFMA flash attention v12
// 8 waves x 512 threads, 128 q-rows/block (16 per wave, ONE group). Same
// verified per-group math as v11's group-0; same K single-buffer + V dbuf
// (48KB). 2 blocks/CU -> 16 waves/CU = 4/SIMD (2x v11's TLP).
__global__ __launch_bounds__(512, 4) void attn_mfma12(const f16_t* __restrict__ Qp,
                                                      const f16_t* __restrict__ Kp,
                                                      const f16_t* __restrict__ Vtp,
                                                      const int* __restrict__ mask,
                                                      const int* __restrict__ flags,
                                                      f16_t* __restrict__ ctx,
                                                      int seq_len) {
    __shared__ __align__(16) f16_t Ksh[2][4096];      // single K tile, [64-key sub-tile][...]
    __shared__ __align__(16) f16_t Vsh[2][2][4096];   // dbuf V^T: [buf][sub-tile][d][key]

    const int tid  = threadIdx.x;
    const int wv   = tid >> 6;        // [0,8)
    const int lane = tid & 63;
    const int quad = lane >> 4;
    const int l15  = lane & 15;
    const int bh   = blockIdx.y;
    const int b    = bh >> 4;
    const int h    = bh & 15;
    const int q0   = blockIdx.x * 128 + wv * 16;

    const long kb = (long)bh * SS * DKK;

    f16x8 qf[2];
    {
        const f16_t* pq = Qp + kb + (long)(q0 + l15) * DKK + quad * 8;
        qf[0] = *(const f16x8*)pq;
        qf[1] = *(const f16x8*)(pq + 32);
        const f16_t qs = (f16_t)(8.0f * 1.44269504088896f);
#pragma unroll
        for (int j = 0; j < 8; ++j) { qf[0][j] *= qs; qf[1][j] *= qs; }
    }

    f16x4 ones4;
#pragma unroll
    for (int j = 0; j < 4; ++j) ones4[j] = (f16_t)1.0f;

    f32x4 o[4], lacc;
#pragma unroll
    for (int r = 0; r < 4; ++r) o[r] = (f32x4){0.f, 0.f, 0.f, 0.f};
    lacc = (f32x4){0.f, 0.f, 0.f, 0.f};
    float m = -1e30f;   // running max for q = l15

    const int* mrow = mask + b * SS;
    const int* frow = flags + b * (SS / 128);

    const int srow8 = lane >> 3;
    const int gcolB = ((lane & 7) ^ srow8) * 8;
    const int NT = seq_len >> 7;

    // prologue: stage K(0) -> Ksh, V(0) -> Vsh[0]; wave wv stages chunk wv per sub-tile
#pragma unroll
    for (int c = 0; c < 2; ++c) {
        const int row = wv * 8 + srow8;
        GLD_LDS(Kp + kb + (long)(c * 64 + row) * DKK + gcolB, &Ksh[c][wv * 512]);
        GLD_LDS(Vtp + kb + (long)row * SS + c * 64 + gcolB, &Vsh[0][c][wv * 512]);
    }

#pragma unroll 1
    for (int tt = 0; tt < NT; ++tt) {
        const int cur = tt & 1;
        const int kt = tt << 7;
        __syncthreads();   // B_top: K(tt) and V(tt)=Vsh[cur] staged (vmcnt drained)

        // QK^T swapped: s[nt][r] = S[key = (nt>>2)*64+(nt&3)*16+quad*4+r][q = l15]
        f32x4 s[8];
#pragma unroll
        for (int nt = 0; nt < 8; ++nt) s[nt] = (f32x4){0.f, 0.f, 0.f, 0.f};
#pragma unroll
        for (int nt = 0; nt < 8; ++nt) {
            const int c = nt >> 2;
            const int kr = (nt & 3) * 16 + l15;
#pragma unroll
            for (int dt = 0; dt < 2; ++dt) {
                f16x8 kf = *(const f16x8*)&Ksh[c][kr * 64 + (((dt * 4 + quad) ^ (l15 & 7)) << 3)];
                s[nt] = __builtin_amdgcn_mfma_f32_16x16x32_f16(kf, qf[dt], s[nt], 0, 0, 0);
            }
        }

        __syncthreads();   // B_mid: all waves done reading Ksh -> safe to restage
        if (tt + 1 < NT) {
            const int kn = (tt + 1) << 7;
#pragma unroll
            for (int c = 0; c < 2; ++c) {
                const int row = wv * 8 + srow8;
                GLD_LDS(Kp + kb + (long)(kn + c * 64 + row) * DKK + gcolB, &Ksh[c][wv * 512]);
                GLD_LDS(Vtp + kb + (long)row * SS + kn + c * 64 + gcolB, &Vsh[cur ^ 1][c][wv * 512]);
            }
        }

        if (!frow[kt >> 7]) {
#pragma unroll
            for (int nt = 0; nt < 8; ++nt) {
                i32x4 kp = *(const i32x4*)&mrow[kt + nt * 16 + quad * 4];
#pragma unroll
                for (int r = 0; r < 4; ++r)
                    s[nt][r] = kp[r] ? s[nt][r] : -1e30f;
            }
        }

        // max over this q-row's keys: in-lane (32 keys) then across the 4 quads
        f32x4 mx;
#pragma unroll
        for (int r = 0; r < 4; ++r)
            mx[r] = fmaxf(fmaxf(fmaxf(s[0][r], s[1][r]), fmaxf(s[2][r], s[3][r])),
                          fmaxf(fmaxf(s[4][r], s[5][r]), fmaxf(s[6][r], s[7][r])));
        float tm = fmaxf(fmaxf(mx[0], mx[1]), fmaxf(mx[2], mx[3]));
        tm = fmaxf(tm, __shfl_xor(tm, 16));
        tm = fmaxf(tm, __shfl_xor(tm, 32));

        const float mn = fmaxf(m, tm);
        if (__any(tm > m)) {
            const float alpha = exp2f(m - mn);
            float a4[4];
#pragma unroll
            for (int r = 0; r < 4; ++r) a4[r] = __shfl(alpha, quad * 4 + r);
#pragma unroll
            for (int t = 0; t < 4; ++t)
#pragma unroll
                for (int r = 0; r < 4; ++r) o[t][r] *= a4[r];
#pragma unroll
            for (int r = 0; r < 4; ++r) lacc[r] *= a4[r];
        }
        m = mn;

        // per 16-key group: exp -> pack -> rowsum MFMA + PV MFMAs
#pragma unroll
        for (int nt = 0; nt < 8; ++nt) {
            const int c = nt >> 2;
            i32x2 pp;
            pp[0] = pkrtz(exp2f(s[nt][0] - mn), exp2f(s[nt][1] - mn));
            pp[1] = pkrtz(exp2f(s[nt][2] - mn), exp2f(s[nt][3] - mn));
            f16x4 paf = __builtin_bit_cast(f16x4, pp);
            lacc = __builtin_amdgcn_mfma_f32_16x16x16f16(paf, ones4, lacc, 0, 0, 0);
            const int vcol = ((((nt & 3) * 2 + (quad >> 1)) ^ (l15 & 7)) << 3) + ((quad & 1) << 2);
#pragma unroll
            for (int t = 0; t < 4; ++t) {
                f16x4 vB = *(const f16x4*)&Vsh[cur][c][(t * 16 + l15) * 64 + vcol];
                o[t] = __builtin_amdgcn_mfma_f32_16x16x16f16(paf, vB, o[t], 0, 0, 0);
            }
        }
    }

    float inv[4];
#pragma unroll
    for (int r = 0; r < 4; ++r) inv[r] = 1.0f / lacc[r];
#pragma unroll
    for (int t = 0; t < 4; ++t) {
        int d = t * 16 + l15;
#pragma unroll
        for (int r = 0; r < 4; ++r) {
            int tok = b * SS + q0 + quad * 4 + r;
            ctx[(long)tok * DD + h * DKK + d] = (f16_t)(o[t][r] * inv[r]);
        }
    }
}

// ---------------------------------------------------------------- launch
extern "C" void kernel_launch(void* const* d_in, const int* in_sizes, int n_in,
                              void* d_out, int out_size, void* d_ws, size_t ws_size,
                              hipStream_t stream) {
    const float* x  = (const float*)d_in[0];
    const int* mask = (const int*)d_in[1];
    const float* Wq = (const float*)d_in[2];
    const float* bq = (const float*)d_in[3];
    const float* Wk = (const float*)d_in[4];
    const float* bk = (const float*)d_in[5];
    const float* Wv = (const float*)d_in[6];
    const float* bv = (const float*)d_in[7];
    const float* Wo = (const float*)d_in[8];
    const float* bo = (const float*)d_in[9];
    float* out = (float*)d_out;

    const long NX = (long)BB * SS * DD;  // 4194304
    const long NW = (long)DD * DD;       // 1048576

    char* ws = (char*)d_ws;
    f16_t* xf   = (f16_t*)ws; ws += NX * 2;
    f16_t* wqkh = (f16_t*)ws; ws += 2 * NW * 2;
    f16_t* wqkl = (f16_t*)ws; ws += 2 * NW * 2;
    f16_t* wvf  = (f16_t*)ws; ws += NW * 2;
    f16_t* wof  = (f16_t*)ws; ws += NW * 2;
    f16_t* qf   = (f16_t*)ws; ws += NX * 2;
    f16_t* kf   = (f16_t*)ws; ws += NX * 2;
    f16_t* vt   = (f16_t*)ws; ws += NX * 2;
    f16_t* ctx  = (f16_t*)ws; ws += NX * 2;
    int*   flg  = (int*)ws;   ws += 64 * 4;

    prep_all<<<2048, 256, 0, stream>>>(x, mask, Wq, Wk, Wv, Wo,
                                       xf, wqkh, wqkl, wvf, wof, flg);

    dim3 gqkv(3 * DD / 128, (BB * SS) / 128);  // (24, 32) = 768 blocks
    gemm_qkv<<<gqkv, 256, 0, stream>>>(xf, wqkh, wqkl, wvf, bq, bk, bv, qf, kf, vt, DD);

    dim3 agrid(SS / 128, BH);  // (16, 32) = 512 blocks, 128 q-rows each, 8 waves
    attn_mfma12<<<agrid, 512, 0, stream>>>(qf, kf, vt, mask, flg, ctx, SS);

    dim3 go(DD / 128, (BB * SS) / 64);  // (8, 64) = 512 blocks
    gemm_o<<<go, 256, 0, stream>>>(ctx, wof, bo, out, DD, DD);
}

// Round 12
// 249.182 us; speedup vs baseline: 1.1144x; 1.0549x over previous
//
#include <hip/hip_runtime.h>
#include <hip/hip_bf16.h>
#include <math.h>

#define BB 2
#define SS 2048
#define DD 1024
#define HH 16
#define DKK 64
#define BH (BB * HH)          // 32

typedef __bf16 bf16_t;
typedef _Float16 f16_t;
typedef __attribute__((ext_vector_type(8))) _Float16 f16x8;
typedef __attribute__((ext_vector_type(4))) _Float16 f16x4;
typedef __attribute__((ext_vector_type(4))) float f32x4;
typedef __attribute__((ext_vector_type(4))) int i32x4;
typedef __attribute__((ext_vector_type(2))) int i32x2;

// async global->LDS, 16B per lane; lds base must be wave-uniform (lane*16 implicit)
#define GLD_LDS(gp, lp) __builtin_amdgcn_global_load_lds( \
    (const __attribute__((address_space(1))) void*)(gp),  \
    (__attribute__((address_space(3))) void*)(lp), 16, 0, 0)

static __device__ __forceinline__ int pkrtz(float a, float b) {
    auto h = __builtin_amdgcn_cvt_pkrtz(a, b);  // __fp16 ext_vector(2) on this clang
    return __builtin_bit_cast(int, h);
}

// ---------------------------------------------------------------- merged prep kernel
__global__ void prep_all(const float* __restrict__ x, const int* __restrict__ mask,
                         const float* __restrict__ Wq, const float* __restrict__ Wk,
                         const float* __restrict__ Wv, const float* __restrict__ Wo,
                         f16_t* __restrict__ xf,
                         f16_t* __restrict__ wqkh, f16_t* __restrict__ wqkl,
                         f16_t* __restrict__ wvf, f16_t* __restrict__ wof,
                         int* __restrict__ flags) {
    const int NXi = BB * SS * DD;   // 4194304
    const int NWi = DD * DD;        // 1048576
    const int total = NXi + 4 * NWi;
    int i = blockIdx.x * blockDim.x + threadIdx.x;
    const int stride = gridDim.x * blockDim.x;
    for (; i < total; i += stride) {
        if (i < NXi) {
            xf[i] = (f16_t)x[i];
        } else if (i < NXi + 2 * NWi) {
            const int j = i - NXi;
            const float v = (j < NWi) ? Wq[j] : Wk[j - NWi];
            const f16_t h = (f16_t)v;
            wqkh[j] = h;
            wqkl[j] = (f16_t)(v - (float)h);
        } else {
            const int j = i - NXi - 2 * NWi;
            if (j < NWi) wvf[j] = (f16_t)Wv[j];
            else         wof[j - NWi] = (f16_t)Wo[j - NWi];
        }
    }
    if (blockIdx.x == 0 && threadIdx.x < BB * (SS / 128)) {
        const int f = threadIdx.x;
        const int b = f / (SS / 128), t = f % (SS / 128);
        const int* p = mask + b * SS + t * 128;
        int all = 1;
        for (int j = 0; j < 128; ++j) all &= (p[j] != 0);
        flags[f] = all;
    }
}

// ---------------------------------------------------------------- fused QKV GEMM (fp16)
// BK=64, XOR-swizzled LDS (attn-verified pattern): 16 K-steps, conflict-free
// ds_read_b128, 12 GLD_LDS in flight per drain. 48KB LDS -> 3 blocks/CU.
__global__ __launch_bounds__(256) void gemm_qkv(const f16_t* __restrict__ Af,
                                                const f16_t* __restrict__ Wqkh,
                                                const f16_t* __restrict__ Wqkl,
                                                const f16_t* __restrict__ Wvf,
                                                const float* __restrict__ bq,
                                                const float* __restrict__ bk,
                                                const float* __restrict__ bv,
                                                f16_t* __restrict__ q_o,
                                                f16_t* __restrict__ k_o,
                                                f16_t* __restrict__ vt_o,
                                                int K) {
    __shared__ __align__(16) f16_t sA[8192];   // 128 rows x 64 f16 (128B rows)
    __shared__ __align__(16) f16_t sB0[8192];
    __shared__ __align__(16) f16_t sB1[8192];

    const int tid  = threadIdx.x;
    const int wv   = tid >> 6;
    const int lane = tid & 63;
    const int quad = lane >> 4;
    const int l15  = lane & 15;
    const int wr   = wv >> 1;
    const int wc   = wv & 1;
    const int row0 = blockIdx.y * 128;
    const int col0 = blockIdx.x * 128;
    const bool isV = (col0 >= 2048);

    const f16_t* B0 = isV ? (Wvf + (long)(col0 - 2048) * K) : (Wqkh + (long)col0 * K);
    const f16_t* B1 = isV ? nullptr : (Wqkl + (long)col0 * K);

    f32x4 acc[4][4] = {};

    // staging: wave wv covers rows p*32 + wv*8 + (lane>>3), swizzled col
    const int srow8 = lane >> 3;                   // row-within-8 (= row & 7)
    const int gsw   = ((lane & 7) ^ srow8) * 8;    // pre-swizzled global col
    const long aoff = (long)(row0 + wv * 8 + srow8) * K + gsw;
    const long boff = (long)(wv * 8 + srow8) * K + gsw;
    const int lsw   = l15 & 7;                     // read-side row&7

    if (isV) {
#pragma unroll 1
        for (int kb = 0; kb < K; kb += 64) {
#pragma unroll
            for (int p = 0; p < 4; ++p) {
                const long go = (long)p * 32 * K + kb;
                const int lo = p * 2048 + wv * 512;
                GLD_LDS(Af + aoff + go, sA + lo);
                GLD_LDS(B0 + boff + go, sB0 + lo);
            }
            __syncthreads();
#pragma unroll
            for (int kk = 0; kk < 2; ++kk) {
                f16x8 af[4];
#pragma unroll
                for (int mt = 0; mt < 4; ++mt)
                    af[mt] = *(const f16x8*)&sA[(wr * 64 + mt * 16 + l15) * 64 + (((kk * 4 + quad) ^ lsw) << 3)];
#pragma unroll
                for (int nt = 0; nt < 4; ++nt) {
                    f16x8 b0 = *(const f16x8*)&sB0[(wc * 64 + nt * 16 + l15) * 64 + (((kk * 4 + quad) ^ lsw) << 3)];
#pragma unroll
                    for (int mt = 0; mt < 4; ++mt)
                        acc[mt][nt] = __builtin_amdgcn_mfma_f32_16x16x32_f16(af[mt], b0, acc[mt][nt], 0, 0, 0);
                }
            }
            __syncthreads();
        }
    } else {
#pragma unroll 1
        for (int kb = 0; kb < K; kb += 64) {
#pragma unroll
            for (int p = 0; p < 4; ++p) {
                const long go = (long)p * 32 * K + kb;
                const int lo = p * 2048 + wv * 512;
                GLD_LDS(Af + aoff + go, sA + lo);
                GLD_LDS(B0 + boff + go, sB0 + lo);
                GLD_LDS(B1 + boff + go, sB1 + lo);
            }
            __syncthreads();
#pragma unroll
            for (int kk = 0; kk < 2; ++kk) {
                f16x8 af[4];
#pragma unroll
                for (int mt = 0; mt < 4; ++mt)
                    af[mt] = *(const f16x8*)&sA[(wr * 64 + mt * 16 + l15) * 64 + (((kk * 4 + quad) ^ lsw) << 3)];
#pragma unroll
                for (int nt = 0; nt < 4; ++nt) {
                    f16x8 b0 = *(const f16x8*)&sB0[(wc * 64 + nt * 16 + l15) * 64 + (((kk * 4 + quad) ^ lsw) << 3)];
                    f16x8 b1 = *(const f16x8*)&sB1[(wc * 64 + nt * 16 + l15) * 64 + (((kk * 4 + quad) ^ lsw) << 3)];
#pragma unroll
                    for (int mt = 0; mt < 4; ++mt) {
                        acc[mt][nt] = __builtin_amdgcn_mfma_f32_16x16x32_f16(af[mt], b0, acc[mt][nt], 0, 0, 0);
                        acc[mt][nt] = __builtin_amdgcn_mfma_f32_16x16x32_f16(af[mt], b1, acc[mt][nt], 0, 0, 0);
                    }
                }
            }
            __syncthreads();
        }
    }

    if (isV) {
#pragma unroll
        for (int nt = 0; nt < 4; ++nt) {
            const int colv = (col0 - 2048) + wc * 64 + nt * 16 + l15;  // [0,1024)
            const float bvv = bv[colv];
            const int hq = colv >> 6, dk = colv & 63;
#pragma unroll
            for (int mt = 0; mt < 4; ++mt) {
                const int grow0 = row0 + wr * 64 + mt * 16 + quad * 4;
                const int bq2 = grow0 >> 11;
                const int s0  = grow0 & (SS - 1);
                f16x4 pk;
#pragma unroll
                for (int r = 0; r < 4; ++r) pk[r] = (f16_t)(acc[mt][nt][r] + bvv);
                *(f16x4*)(vt_o + ((long)(bq2 * HH + hq) * DKK + dk) * SS + s0) = pk;
            }
        }
    } else {
        const bool isK = (col0 >= 1024);
        const float* bias = isK ? bk : bq;
        f16_t* op = isK ? k_o : q_o;
#pragma unroll
        for (int nt = 0; nt < 4; ++nt) {
            const int gcol = (col0 & 1023) + wc * 64 + nt * 16 + l15;
            const float bvv = bias[gcol];
            const int hq = gcol >> 6, dk = gcol & 63;
#pragma unroll
            for (int mt = 0; mt < 4; ++mt) {
                const int grow0 = row0 + wr * 64 + mt * 16 + quad * 4;
#pragma unroll
                for (int r = 0; r < 4; ++r) {
                    int grow = grow0 + r;
                    float vvv = acc[mt][nt][r] + bvv;
                    long off = (((long)(grow >> 11) * HH + hq) * SS + (grow & (SS - 1))) * DKK + dk;
                    op[off] = (f16_t)vvv;
                }
            }
        }
    }
}

// ---------------------------------------------------------------- O-projection GEMM (fp16 in, fp32 out)
__global__ __launch_bounds__(256) void gemm_o(const f16_t* __restrict__ Ah,
                                              const f16_t* __restrict__ Bhp,
                                              const float* __restrict__ bias,
                                              float* __restrict__ outf,
                                              int N, int K) {
    __shared__ __align__(16) f16_t lds[2048 + 4096];
    f16_t* Ash = lds;
    f16_t* Bsh = lds + 2048;

    const int tid  = threadIdx.x;
    const int wv   = tid >> 6;
    const int lane = tid & 63;
    const int quad = lane >> 4;
    const int l15  = lane & 15;
    const int wr   = wv >> 1;
    const int wc   = wv & 1;
    const int row0 = blockIdx.y * 64;
    const int col0 = blockIdx.x * 128;

    f32x4 acc[2][4] = {};

    const int srow = lane >> 2;
    const int scol = (lane & 3) * 8;
    const f16_t* gA  = Ah  + (long)(row0 + wv * 16 + srow) * K + scol;
    const f16_t* gB0 = Bhp + (long)(col0 + wv * 16 + srow) * K + scol;
    const f16_t* gB1 = Bhp + (long)(col0 + (wv + 4) * 16 + srow) * K + scol;
    f16_t* lA  = Ash + wv * 512;
    f16_t* lB0 = Bsh + wv * 512;
    f16_t* lB1 = Bsh + (wv + 4) * 512;

#pragma unroll 1
    for (int kb = 0; kb < K; kb += 32) {
        GLD_LDS(gA + kb, lA);
        GLD_LDS(gB0 + kb, lB0);
        GLD_LDS(gB1 + kb, lB1);
        __syncthreads();

        f16x8 af[2];
#pragma unroll
        for (int mt = 0; mt < 2; ++mt)
            af[mt] = *(const f16x8*)&Ash[(wr * 32 + mt * 16 + l15) * 32 + quad * 8];
#pragma unroll
        for (int nt = 0; nt < 4; ++nt) {
            f16x8 bh = *(const f16x8*)&Bsh[(wc * 64 + nt * 16 + l15) * 32 + quad * 8];
#pragma unroll
            for (int mt = 0; mt < 2; ++mt)
                acc[mt][nt] = __builtin_amdgcn_mfma_f32_16x16x32_f16(af[mt], bh, acc[mt][nt], 0, 0, 0);
        }
        __syncthreads();
    }

#pragma unroll
    for (int mt = 0; mt < 2; ++mt) {
#pragma unroll
        for (int nt = 0; nt < 4; ++nt) {
            const int gcol  = col0 + wc * 64 + nt * 16 + l15;
            const float bvv = bias[gcol];
            const int grow0 = row0 + wr * 32 + mt * 16 + quad * 4;
#pragma unroll
            for (int r = 0; r < 4; ++r)
                outf[(long)(grow0 + r) * N + gcol] = acc[mt][nt][r] + bvv;
        }
    }
}

// ---------------------------------------------------------------- MFMA flash attention v12
// (unchanged from round 11: attn no longer the top dispatch)
__global__ __launch_bounds__(512, 4) void attn_mfma12(const f16_t* __restrict__ Qp,
                                                      const f16_t* __restrict__ Kp,
                                                      const f16_t* __restrict__ Vtp,
                                                      const int* __restrict__ mask,
                                                      const int* __restrict__ flags,
                                                      f16_t* __restrict__ ctx,
                                                      int seq_len) {
    __shared__ __align__(16) f16_t Ksh[2][4096];      // single K tile, [64-key sub-tile][...]
    __shared__ __align__(16) f16_t Vsh[2][2][4096];   // dbuf V^T: [buf][sub-tile][d][key]

    const int tid  = threadIdx.x;
    const int wv   = tid >> 6;        // [0,8)
    const int lane = tid & 63;
    const int quad = lane >> 4;
    const int l15  = lane & 15;
    const int bh   = blockIdx.y;
    const int b    = bh >> 4;
    const int h    = bh & 15;
    const int q0   = blockIdx.x * 128 + wv * 16;

    const long kb = (long)bh * SS * DKK;

    f16x8 qf[2];
    {
        const f16_t* pq = Qp + kb + (long)(q0 + l15) * DKK + quad * 8;
        qf[0] = *(const f16x8*)pq;
        qf[1] = *(const f16x8*)(pq + 32);
        const f16_t qs = (f16_t)(8.0f * 1.44269504088896f);
#pragma unroll
        for (int j = 0; j < 8; ++j) { qf[0][j] *= qs; qf[1][j] *= qs; }
    }

    f16x4 ones4;
#pragma unroll
    for (int j = 0; j < 4; ++j) ones4[j] = (f16_t)1.0f;

    f32x4 o[4], lacc;
#pragma unroll
    for (int r = 0; r < 4; ++r) o[r] = (f32x4){0.f, 0.f, 0.f, 0.f};
    lacc = (f32x4){0.f, 0.f, 0.f, 0.f};
    float m = -1e30f;   // running max for q = l15

    const int* mrow = mask + b * SS;
    const int* frow = flags + b * (SS / 128);

    const int srow8 = lane >> 3;
    const int gcolB = ((lane & 7) ^ srow8) * 8;
    const int NT = seq_len >> 7;

    // prologue: stage K(0) -> Ksh, V(0) -> Vsh[0]; wave wv stages chunk wv per sub-tile
#pragma unroll
    for (int c = 0; c < 2; ++c) {
        const int row = wv * 8 + srow8;
        GLD_LDS(Kp + kb + (long)(c * 64 + row) * DKK + gcolB, &Ksh[c][wv * 512]);
        GLD_LDS(Vtp + kb + (long)row * SS + c * 64 + gcolB, &Vsh[0][c][wv * 512]);
    }

#pragma unroll 1
    for (int tt = 0; tt < NT; ++tt) {
        const int cur = tt & 1;
        const int kt = tt << 7;
        __syncthreads();   // B_top: K(tt) and V(tt)=Vsh[cur] staged (vmcnt drained)

        // QK^T swapped: s[nt][r] = S[key = (nt>>2)*64+(nt&3)*16+quad*4+r][q = l15]
        f32x4 s[8];
#pragma unroll
        for (int nt = 0; nt < 8; ++nt) s[nt] = (f32x4){0.f, 0.f, 0.f, 0.f};
#pragma unroll
        for (int nt = 0; nt < 8; ++nt) {
            const int c = nt >> 2;
            const int kr = (nt & 3) * 16 + l15;
#pragma unroll
            for (int dt = 0; dt < 2; ++dt) {
                f16x8 kf = *(const f16x8*)&Ksh[c][kr * 64 + (((dt * 4 + quad) ^ (l15 & 7)) << 3)];
                s[nt] = __builtin_amdgcn_mfma_f32_16x16x32_f16(kf, qf[dt], s[nt], 0, 0, 0);
            }
        }

        __syncthreads();   // B_mid: all waves done reading Ksh -> safe to restage
        if (tt + 1 < NT) {
            const int kn = (tt + 1) << 7;
#pragma unroll
            for (int c = 0; c < 2; ++c) {
                const int row = wv * 8 + srow8;
                GLD_LDS(Kp + kb + (long)(kn + c * 64 + row) * DKK + gcolB, &Ksh[c][wv * 512]);
                GLD_LDS(Vtp + kb + (long)row * SS + kn + c * 64 + gcolB, &Vsh[cur ^ 1][c][wv * 512]);
            }
        }

        if (!frow[kt >> 7]) {
#pragma unroll
            for (int nt = 0; nt < 8; ++nt) {
                i32x4 kp = *(const i32x4*)&mrow[kt + nt * 16 + quad * 4];
#pragma unroll
                for (int r = 0; r < 4; ++r)
                    s[nt][r] = kp[r] ? s[nt][r] : -1e30f;
            }
        }

        // max over this q-row's keys: in-lane (32 keys) then across the 4 quads
        f32x4 mx;
#pragma unroll
        for (int r = 0; r < 4; ++r)
            mx[r] = fmaxf(fmaxf(fmaxf(s[0][r], s[1][r]), fmaxf(s[2][r], s[3][r])),
                          fmaxf(fmaxf(s[4][r], s[5][r]), fmaxf(s[6][r], s[7][r])));
        float tm = fmaxf(fmaxf(mx[0], mx[1]), fmaxf(mx[2], mx[3]));
        tm = fmaxf(tm, __shfl_xor(tm, 16));
        tm = fmaxf(tm, __shfl_xor(tm, 32));

        const float mn = fmaxf(m, tm);
        if (__any(tm > m)) {
            const float alpha = exp2f(m - mn);
            float a4[4];
#pragma unroll
            for (int r = 0; r < 4; ++r) a4[r] = __shfl(alpha, quad * 4 + r);
#pragma unroll
            for (int t = 0; t < 4; ++t)
#pragma unroll
                for (int r = 0; r < 4; ++r) o[t][r] *= a4[r];
#pragma unroll
            for (int r = 0; r < 4; ++r) lacc[r] *= a4[r];
        }
        m = mn;

        // per 16-key group: exp -> pack -> rowsum MFMA + PV MFMAs
#pragma unroll
        for (int nt = 0; nt < 8; ++nt) {
            const int c = nt >> 2;
            i32x2 pp;
            pp[0] = pkrtz(exp2f(s[nt][0] - mn), exp2f(s[nt][1] - mn));
            pp[1] = pkrtz(exp2f(s[nt][2] - mn), exp2f(s[nt][3] - mn));
            f16x4 paf = __builtin_bit_cast(f16x4, pp);
            lacc = __builtin_amdgcn_mfma_f32_16x16x16f16(paf, ones4, lacc, 0, 0, 0);
            const int vcol = ((((nt & 3) * 2 + (quad >> 1)) ^ (l15 & 7)) << 3) + ((quad & 1) << 2);
#pragma unroll
            for (int t = 0; t < 4; ++t) {
                f16x4 vB = *(const f16x4*)&Vsh[cur][c][(t * 16 + l15) * 64 + vcol];
                o[t] = __builtin_amdgcn_mfma_f32_16x16x16f16(paf, vB, o[t], 0, 0, 0);
            }
        }
    }

    float inv[4];
#pragma unroll
    for (int r = 0; r < 4; ++r) inv[r] = 1.0f / lacc[r];
#pragma unroll
    for (int t = 0; t < 4; ++t) {
        int d = t * 16 + l15;
#pragma unroll
        for (int r = 0; r < 4; ++r) {
            int tok = b * SS + q0 + quad * 4 + r;
            ctx[(long)tok * DD + h * DKK + d] = (f16_t)(o[t][r] * inv[r]);
        }
    }
}

// ---------------------------------------------------------------- launch
extern "C" void kernel_launch(void* const* d_in, const int* in_sizes, int n_in,
                              void* d_out, int out_size, void* d_ws, size_t ws_size,
                              hipStream_t stream) {
    const float* x  = (const float*)d_in[0];
    const int* mask = (const int*)d_in[1];
    const float* Wq = (const float*)d_in[2];
    const float* bq = (const float*)d_in[3];
    const float* Wk = (const float*)d_in[4];
    const float* bk = (const float*)d_in[5];
    const float* Wv = (const float*)d_in[6];
    const float* bv = (const float*)d_in[7];
    const float* Wo = (const float*)d_in[8];
    const float* bo = (const float*)d_in[9];
    float* out = (float*)d_out;

    const long NX = (long)BB * SS * DD;  // 4194304
    const long NW = (long)DD * DD;       // 1048576

    char* ws = (char*)d_ws;
    f16_t* xf   = (f16_t*)ws; ws += NX * 2;
    f16_t* wqkh = (f16_t*)ws; ws += 2 * NW * 2;
    f16_t* wqkl = (f16_t*)ws; ws += 2 * NW * 2;
    f16_t* wvf  = (f16_t*)ws; ws += NW * 2;
    f16_t* wof  = (f16_t*)ws; ws += NW * 2;
    f16_t* qf   = (f16_t*)ws; ws += NX * 2;
    f16_t* kf   = (f16_t*)ws; ws += NX * 2;
    f16_t* vt   = (f16_t*)ws; ws += NX * 2;
    f16_t* ctx  = (f16_t*)ws; ws += NX * 2;
    int*   flg  = (int*)ws;   ws += 64 * 4;

    prep_all<<<2048, 256, 0, stream>>>(x, mask, Wq, Wk, Wv, Wo,
                                       xf, wqkh, wqkl, wvf, wof, flg);

    dim3 gqkv(3 * DD / 128, (BB * SS) / 128);  // (24, 32) = 768 blocks
    gemm_qkv<<<gqkv, 256, 0, stream>>>(xf, wqkh, wqkl, wvf, bq, bk, bv, qf, kf, vt, DD);

    dim3 agrid(SS / 128, BH);  // (16, 32) = 512 blocks, 128 q-rows each, 8 waves
    attn_mfma12<<<agrid, 512, 0, stream>>>(qf, kf, vt, mask, flg, ctx, SS);

    dim3 go(DD / 128, (BB * SS) / 64);  // (8, 64) = 512 blocks
    gemm_o<<<go, 256, 0, stream>>>(ctx, wof, bo, out, DD, DD);
}

// Round 13
// 239.649 us; speedup vs baseline: 1.1587x; 1.0398x over previous
//
#include <hip/hip_runtime.h>
#include <hip/hip_bf16.h>
#include <math.h>

#define BB 2
#define SS 2048
#define DD 1024
#define HH 16
#define DKK 64
#define BH (BB * HH)          // 32

typedef __bf16 bf16_t;
typedef _Float16 f16_t;
typedef __attribute__((ext_vector_type(8))) _Float16 f16x8;
typedef __attribute__((ext_vector_type(4))) _Float16 f16x4;
typedef __attribute__((ext_vector_type(4))) float f32x4;
typedef __attribute__((ext_vector_type(4))) int i32x4;
typedef __attribute__((ext_vector_type(2))) int i32x2;

// async global->LDS, 16B per lane; lds base must be wave-uniform (lane*16 implicit)
#define GLD_LDS(gp, lp) __builtin_amdgcn_global_load_lds( \
    (const __attribute__((address_space(1))) void*)(gp),  \
    (__attribute__((address_space(3))) void*)(lp), 16, 0, 0)

static __device__ __forceinline__ int pkrtz(float a, float b) {
    auto h = __builtin_amdgcn_cvt_pkrtz(a, b);  // __fp16 ext_vector(2) on this clang
    return __builtin_bit_cast(int, h);
}

// ---------------------------------------------------------------- merged prep kernel
__global__ void prep_all(const float* __restrict__ x, const int* __restrict__ mask,
                         const float* __restrict__ Wq, const float* __restrict__ Wk,
                         const float* __restrict__ Wv, const float* __restrict__ Wo,
                         f16_t* __restrict__ xf,
                         f16_t* __restrict__ wqkh, f16_t* __restrict__ wqkl,
                         f16_t* __restrict__ wvf, f16_t* __restrict__ wof,
                         int* __restrict__ flags) {
    const int NXi = BB * SS * DD;   // 4194304
    const int NWi = DD * DD;        // 1048576
    const int total = NXi + 4 * NWi;
    int i = blockIdx.x * blockDim.x + threadIdx.x;
    const int stride = gridDim.x * blockDim.x;
    for (; i < total; i += stride) {
        if (i < NXi) {
            xf[i] = (f16_t)x[i];
        } else if (i < NXi + 2 * NWi) {
            const int j = i - NXi;
            const float v = (j < NWi) ? Wq[j] : Wk[j - NWi];
            const f16_t h = (f16_t)v;
            wqkh[j] = h;
            wqkl[j] = (f16_t)(v - (float)h);
        } else {
            const int j = i - NXi - 2 * NWi;
            if (j < NWi) wvf[j] = (f16_t)Wv[j];
            else         wof[j - NWi] = (f16_t)Wo[j - NWi];
        }
    }
    if (blockIdx.x == 0 && threadIdx.x < BB * (SS / 128)) {
        const int f = threadIdx.x;
        const int b = f / (SS / 128), t = f % (SS / 128);
        const int* p = mask + b * SS + t * 128;
        int all = 1;
        for (int j = 0; j < 128; ++j) all &= (p[j] != 0);
        flags[f] = all;
    }
}

// ---------------------------------------------------------------- fused QKV GEMM (fp16)
// BK=64, XOR-swizzled LDS: 16 K-steps, conflict-free ds_read_b128 (verified R12).
__global__ __launch_bounds__(256) void gemm_qkv(const f16_t* __restrict__ Af,
                                                const f16_t* __restrict__ Wqkh,
                                                const f16_t* __restrict__ Wqkl,
                                                const f16_t* __restrict__ Wvf,
                                                const float* __restrict__ bq,
                                                const float* __restrict__ bk,
                                                const float* __restrict__ bv,
                                                f16_t* __restrict__ q_o,
                                                f16_t* __restrict__ k_o,
                                                f16_t* __restrict__ vt_o,
                                                int K) {
    __shared__ __align__(16) f16_t sA[8192];   // 128 rows x 64 f16 (128B rows)
    __shared__ __align__(16) f16_t sB0[8192];
    __shared__ __align__(16) f16_t sB1[8192];

    const int tid  = threadIdx.x;
    const int wv   = tid >> 6;
    const int lane = tid & 63;
    const int quad = lane >> 4;
    const int l15  = lane & 15;
    const int wr   = wv >> 1;
    const int wc   = wv & 1;
    const int row0 = blockIdx.y * 128;
    const int col0 = blockIdx.x * 128;
    const bool isV = (col0 >= 2048);

    const f16_t* B0 = isV ? (Wvf + (long)(col0 - 2048) * K) : (Wqkh + (long)col0 * K);
    const f16_t* B1 = isV ? nullptr : (Wqkl + (long)col0 * K);

    f32x4 acc[4][4] = {};

    const int srow8 = lane >> 3;                   // row-within-8 (= row & 7)
    const int gsw   = ((lane & 7) ^ srow8) * 8;    // pre-swizzled global col
    const long aoff = (long)(row0 + wv * 8 + srow8) * K + gsw;
    const long boff = (long)(wv * 8 + srow8) * K + gsw;
    const int lsw   = l15 & 7;                     // read-side row&7

    if (isV) {
#pragma unroll 1
        for (int kb = 0; kb < K; kb += 64) {
#pragma unroll
            for (int p = 0; p < 4; ++p) {
                const long go = (long)p * 32 * K + kb;
                const int lo = p * 2048 + wv * 512;
                GLD_LDS(Af + aoff + go, sA + lo);
                GLD_LDS(B0 + boff + go, sB0 + lo);
            }
            __syncthreads();
#pragma unroll
            for (int kk = 0; kk < 2; ++kk) {
                f16x8 af[4];
#pragma unroll
                for (int mt = 0; mt < 4; ++mt)
                    af[mt] = *(const f16x8*)&sA[(wr * 64 + mt * 16 + l15) * 64 + (((kk * 4 + quad) ^ lsw) << 3)];
#pragma unroll
                for (int nt = 0; nt < 4; ++nt) {
                    f16x8 b0 = *(const f16x8*)&sB0[(wc * 64 + nt * 16 + l15) * 64 + (((kk * 4 + quad) ^ lsw) << 3)];
#pragma unroll
                    for (int mt = 0; mt < 4; ++mt)
                        acc[mt][nt] = __builtin_amdgcn_mfma_f32_16x16x32_f16(af[mt], b0, acc[mt][nt], 0, 0, 0);
                }
            }
            __syncthreads();
        }
    } else {
#pragma unroll 1
        for (int kb = 0; kb < K; kb += 64) {
#pragma unroll
            for (int p = 0; p < 4; ++p) {
                const long go = (long)p * 32 * K + kb;
                const int lo = p * 2048 + wv * 512;
                GLD_LDS(Af + aoff + go, sA + lo);
                GLD_LDS(B0 + boff + go, sB0 + lo);
                GLD_LDS(B1 + boff + go, sB1 + lo);
            }
            __syncthreads();
#pragma unroll
            for (int kk = 0; kk < 2; ++kk) {
                f16x8 af[4];
#pragma unroll
                for (int mt = 0; mt < 4; ++mt)
                    af[mt] = *(const f16x8*)&sA[(wr * 64 + mt * 16 + l15) * 64 + (((kk * 4 + quad) ^ lsw) << 3)];
#pragma unroll
                for (int nt = 0; nt < 4; ++nt) {
                    f16x8 b0 = *(const f16x8*)&sB0[(wc * 64 + nt * 16 + l15) * 64 + (((kk * 4 + quad) ^ lsw) << 3)];
                    f16x8 b1 = *(const f16x8*)&sB1[(wc * 64 + nt * 16 + l15) * 64 + (((kk * 4 + quad) ^ lsw) << 3)];
#pragma unroll
                    for (int mt = 0; mt < 4; ++mt) {
                        acc[mt][nt] = __builtin_amdgcn_mfma_f32_16x16x32_f16(af[mt], b0, acc[mt][nt], 0, 0, 0);
                        acc[mt][nt] = __builtin_amdgcn_mfma_f32_16x16x32_f16(af[mt], b1, acc[mt][nt], 0, 0, 0);
                    }
                }
            }
            __syncthreads();
        }
    }

    if (isV) {
#pragma unroll
        for (int nt = 0; nt < 4; ++nt) {
            const int colv = (col0 - 2048) + wc * 64 + nt * 16 + l15;  // [0,1024)
            const float bvv = bv[colv];
            const int hq = colv >> 6, dk = colv & 63;
#pragma unroll
            for (int mt = 0; mt < 4; ++mt) {
                const int grow0 = row0 + wr * 64 + mt * 16 + quad * 4;
                const int bq2 = grow0 >> 11;
                const int s0  = grow0 & (SS - 1);
                f16x4 pk;
#pragma unroll
                for (int r = 0; r < 4; ++r) pk[r] = (f16_t)(acc[mt][nt][r] + bvv);
                *(f16x4*)(vt_o + ((long)(bq2 * HH + hq) * DKK + dk) * SS + s0) = pk;
            }
        }
    } else {
        const bool isK = (col0 >= 1024);
        const float* bias = isK ? bk : bq;
        f16_t* op = isK ? k_o : q_o;
#pragma unroll
        for (int nt = 0; nt < 4; ++nt) {
            const int gcol = (col0 & 1023) + wc * 64 + nt * 16 + l15;
            const float bvv = bias[gcol];
            const int hq = gcol >> 6, dk = gcol & 63;
#pragma unroll
            for (int mt = 0; mt < 4; ++mt) {
                const int grow0 = row0 + wr * 64 + mt * 16 + quad * 4;
#pragma unroll
                for (int r = 0; r < 4; ++r) {
                    int grow = grow0 + r;
                    float vvv = acc[mt][nt][r] + bvv;
                    long off = (((long)(grow >> 11) * HH + hq) * SS + (grow & (SS - 1))) * DKK + dk;
                    op[off] = (f16_t)vvv;
                }
            }
        }
    }
}

// ---------------------------------------------------------------- O-projection GEMM (fp16 in, fp32 out)
// Tile 64x128, now BK=64 + XOR swizzle (the R12 gemm_qkv recipe): 16 K-steps,
// conflict-free ds_read_b128, 24KB LDS.
__global__ __launch_bounds__(256) void gemm_o(const f16_t* __restrict__ Ah,
                                              const f16_t* __restrict__ Bhp,
                                              const float* __restrict__ bias,
                                              float* __restrict__ outf,
                                              int N, int K) {
    __shared__ __align__(16) f16_t sA[4096];   // 64 rows x 64 f16
    __shared__ __align__(16) f16_t sB[8192];   // 128 rows x 64 f16

    const int tid  = threadIdx.x;
    const int wv   = tid >> 6;
    const int lane = tid & 63;
    const int quad = lane >> 4;
    const int l15  = lane & 15;
    const int wr   = wv >> 1;
    const int wc   = wv & 1;
    const int row0 = blockIdx.y * 64;
    const int col0 = blockIdx.x * 128;

    f32x4 acc[2][4] = {};

    const int srow8 = lane >> 3;
    const int gsw   = ((lane & 7) ^ srow8) * 8;
    const long aoff = (long)(row0 + wv * 8 + srow8) * K + gsw;
    const long boff = (long)(col0 + wv * 8 + srow8) * K + gsw;
    const int lsw   = l15 & 7;

#pragma unroll 1
    for (int kb = 0; kb < K; kb += 64) {
#pragma unroll
        for (int p = 0; p < 2; ++p) {   // A: 64 rows in 2 passes
            GLD_LDS(Ah + aoff + (long)p * 32 * K + kb, sA + p * 2048 + wv * 512);
        }
#pragma unroll
        for (int p = 0; p < 4; ++p) {   // B: 128 rows in 4 passes
            GLD_LDS(Bhp + boff + (long)p * 32 * K + kb, sB + p * 2048 + wv * 512);
        }
        __syncthreads();

#pragma unroll
        for (int kk = 0; kk < 2; ++kk) {
            f16x8 af[2];
#pragma unroll
            for (int mt = 0; mt < 2; ++mt)
                af[mt] = *(const f16x8*)&sA[(wr * 32 + mt * 16 + l15) * 64 + (((kk * 4 + quad) ^ lsw) << 3)];
#pragma unroll
            for (int nt = 0; nt < 4; ++nt) {
                f16x8 bh = *(const f16x8*)&sB[(wc * 64 + nt * 16 + l15) * 64 + (((kk * 4 + quad) ^ lsw) << 3)];
#pragma unroll
                for (int mt = 0; mt < 2; ++mt)
                    acc[mt][nt] = __builtin_amdgcn_mfma_f32_16x16x32_f16(af[mt], bh, acc[mt][nt], 0, 0, 0);
            }
        }
        __syncthreads();
    }

#pragma unroll
    for (int mt = 0; mt < 2; ++mt) {
#pragma unroll
        for (int nt = 0; nt < 4; ++nt) {
            const int gcol  = col0 + wc * 64 + nt * 16 + l15;
            const float bvv = bias[gcol];
            const int grow0 = row0 + wr * 32 + mt * 16 + quad * 4;
#pragma unroll
            for (int r = 0; r < 4; ++r)
                outf[(long)(grow0 + r) * N + gcol] = acc[mt][nt][r] + bvv;
        }
    }
}

// ---------------------------------------------------------------- MFMA flash attention v13
// v12 + defer-max (T13): rescale only when tm > m + 8 (log2 domain); P bounded
// by 2^8 = 256 << f16 max; rowsum/O in f32; final division normalizes exactly.
__global__ __launch_bounds__(512, 4) void attn_mfma13(const f16_t* __restrict__ Qp,
                                                      const f16_t* __restrict__ Kp,
                                                      const f16_t* __restrict__ Vtp,
                                                      const int* __restrict__ mask,
                                                      const int* __restrict__ flags,
                                                      f16_t* __restrict__ ctx,
                                                      int seq_len) {
    __shared__ __align__(16) f16_t Ksh[2][4096];      // single K tile, [64-key sub-tile][...]
    __shared__ __align__(16) f16_t Vsh[2][2][4096];   // dbuf V^T: [buf][sub-tile][d][key]

    const int tid  = threadIdx.x;
    const int wv   = tid >> 6;        // [0,8)
    const int lane = tid & 63;
    const int quad = lane >> 4;
    const int l15  = lane & 15;
    const int bh   = blockIdx.y;
    const int b    = bh >> 4;
    const int h    = bh & 15;
    const int q0   = blockIdx.x * 128 + wv * 16;

    const long kb = (long)bh * SS * DKK;

    f16x8 qf[2];
    {
        const f16_t* pq = Qp + kb + (long)(q0 + l15) * DKK + quad * 8;
        qf[0] = *(const f16x8*)pq;
        qf[1] = *(const f16x8*)(pq + 32);
        const f16_t qs = (f16_t)(8.0f * 1.44269504088896f);
#pragma unroll
        for (int j = 0; j < 8; ++j) { qf[0][j] *= qs; qf[1][j] *= qs; }
    }

    f16x4 ones4;
#pragma unroll
    for (int j = 0; j < 4; ++j) ones4[j] = (f16_t)1.0f;

    f32x4 o[4], lacc;
#pragma unroll
    for (int r = 0; r < 4; ++r) o[r] = (f32x4){0.f, 0.f, 0.f, 0.f};
    lacc = (f32x4){0.f, 0.f, 0.f, 0.f};
    float m = -1e30f;   // running max for q = l15

    const int* mrow = mask + b * SS;
    const int* frow = flags + b * (SS / 128);

    const int srow8 = lane >> 3;
    const int gcolB = ((lane & 7) ^ srow8) * 8;
    const int NT = seq_len >> 7;

    // prologue: stage K(0) -> Ksh, V(0) -> Vsh[0]; wave wv stages chunk wv per sub-tile
#pragma unroll
    for (int c = 0; c < 2; ++c) {
        const int row = wv * 8 + srow8;
        GLD_LDS(Kp + kb + (long)(c * 64 + row) * DKK + gcolB, &Ksh[c][wv * 512]);
        GLD_LDS(Vtp + kb + (long)row * SS + c * 64 + gcolB, &Vsh[0][c][wv * 512]);
    }

#pragma unroll 1
    for (int tt = 0; tt < NT; ++tt) {
        const int cur = tt & 1;
        const int kt = tt << 7;
        __syncthreads();   // B_top: K(tt) and V(tt)=Vsh[cur] staged (vmcnt drained)

        // QK^T swapped: s[nt][r] = S[key = (nt>>2)*64+(nt&3)*16+quad*4+r][q = l15]
        f32x4 s[8];
#pragma unroll
        for (int nt = 0; nt < 8; ++nt) s[nt] = (f32x4){0.f, 0.f, 0.f, 0.f};
#pragma unroll
        for (int nt = 0; nt < 8; ++nt) {
            const int c = nt >> 2;
            const int kr = (nt & 3) * 16 + l15;
#pragma unroll
            for (int dt = 0; dt < 2; ++dt) {
                f16x8 kf = *(const f16x8*)&Ksh[c][kr * 64 + (((dt * 4 + quad) ^ (l15 & 7)) << 3)];
                s[nt] = __builtin_amdgcn_mfma_f32_16x16x32_f16(kf, qf[dt], s[nt], 0, 0, 0);
            }
        }

        __syncthreads();   // B_mid: all waves done reading Ksh -> safe to restage
        if (tt + 1 < NT) {
            const int kn = (tt + 1) << 7;
#pragma unroll
            for (int c = 0; c < 2; ++c) {
                const int row = wv * 8 + srow8;
                GLD_LDS(Kp + kb + (long)(kn + c * 64 + row) * DKK + gcolB, &Ksh[c][wv * 512]);
                GLD_LDS(Vtp + kb + (long)row * SS + kn + c * 64 + gcolB, &Vsh[cur ^ 1][c][wv * 512]);
            }
        }

        if (!frow[kt >> 7]) {
#pragma unroll
            for (int nt = 0; nt < 8; ++nt) {
                i32x4 kp = *(const i32x4*)&mrow[kt + nt * 16 + quad * 4];
#pragma unroll
                for (int r = 0; r < 4; ++r)
                    s[nt][r] = kp[r] ? s[nt][r] : -1e30f;
            }
        }

        // max over this q-row's keys: in-lane (32 keys) then across the 4 quads
        f32x4 mx;
#pragma unroll
        for (int r = 0; r < 4; ++r)
            mx[r] = fmaxf(fmaxf(fmaxf(s[0][r], s[1][r]), fmaxf(s[2][r], s[3][r])),
                          fmaxf(fmaxf(s[4][r], s[5][r]), fmaxf(s[6][r], s[7][r])));
        float tm = fmaxf(fmaxf(mx[0], mx[1]), fmaxf(mx[2], mx[3]));
        tm = fmaxf(tm, __shfl_xor(tm, 16));
        tm = fmaxf(tm, __shfl_xor(tm, 32));

        // defer-max: only rescale when the max grew by > 8 (log2 domain);
        // otherwise keep old m — P bounded by 2^8, f32 accumulators absorb it.
        if (__any(tm > m + 8.0f)) {
            const float mn = fmaxf(m, tm);
            const float alpha = exp2f(m - mn);
            float a4[4];
#pragma unroll
            for (int r = 0; r < 4; ++r) a4[r] = __shfl(alpha, quad * 4 + r);
#pragma unroll
            for (int t = 0; t < 4; ++t)
#pragma unroll
                for (int r = 0; r < 4; ++r) o[t][r] *= a4[r];
#pragma unroll
            for (int r = 0; r < 4; ++r) lacc[r] *= a4[r];
            m = mn;
        }

        // per 16-key group: exp -> pack -> rowsum MFMA + PV MFMAs
#pragma unroll
        for (int nt = 0; nt < 8; ++nt) {
            const int c = nt >> 2;
            i32x2 pp;
            pp[0] = pkrtz(exp2f(s[nt][0] - m), exp2f(s[nt][1] - m));
            pp[1] = pkrtz(exp2f(s[nt][2] - m), exp2f(s[nt][3] - m));
            f16x4 paf = __builtin_bit_cast(f16x4, pp);
            lacc = __builtin_amdgcn_mfma_f32_16x16x16f16(paf, ones4, lacc, 0, 0, 0);
            const int vcol = ((((nt & 3) * 2 + (quad >> 1)) ^ (l15 & 7)) << 3) + ((quad & 1) << 2);
#pragma unroll
            for (int t = 0; t < 4; ++t) {
                f16x4 vB = *(const f16x4*)&Vsh[cur][c][(t * 16 + l15) * 64 + vcol];
                o[t] = __builtin_amdgcn_mfma_f32_16x16x16f16(paf, vB, o[t], 0, 0, 0);
            }
        }
    }

    float inv[4];
#pragma unroll
    for (int r = 0; r < 4; ++r) inv[r] = 1.0f / lacc[r];
#pragma unroll
    for (int t = 0; t < 4; ++t) {
        int d = t * 16 + l15;
#pragma unroll
        for (int r = 0; r < 4; ++r) {
            int tok = b * SS + q0 + quad * 4 + r;
            ctx[(long)tok * DD + h * DKK + d] = (f16_t)(o[t][r] * inv[r]);
        }
    }
}

// ---------------------------------------------------------------- launch
extern "C" void kernel_launch(void* const* d_in, const int* in_sizes, int n_in,
                              void* d_out, int out_size, void* d_ws, size_t ws_size,
                              hipStream_t stream) {
    const float* x  = (const float*)d_in[0];
    const int* mask = (const int*)d_in[1];
    const float* Wq = (const float*)d_in[2];
    const float* bq = (const float*)d_in[3];
    const float* Wk = (const float*)d_in[4];
    const float* bk = (const float*)d_in[5];
    const float* Wv = (const float*)d_in[6];
    const float* bv = (const float*)d_in[7];
    const float* Wo = (const float*)d_in[8];
    const float* bo = (const float*)d_in[9];
    float* out = (float*)d_out;

    const long NX = (long)BB * SS * DD;  // 4194304
    const long NW = (long)DD * DD;       // 1048576

    char* ws = (char*)d_ws;
    f16_t* xf   = (f16_t*)ws; ws += NX * 2;
    f16_t* wqkh = (f16_t*)ws; ws += 2 * NW * 2;
    f16_t* wqkl = (f16_t*)ws; ws += 2 * NW * 2;
    f16_t* wvf  = (f16_t*)ws; ws += NW * 2;
    f16_t* wof  = (f16_t*)ws; ws += NW * 2;
    f16_t* qf   = (f16_t*)ws; ws += NX * 2;
    f16_t* kf   = (f16_t*)ws; ws += NX * 2;
    f16_t* vt   = (f16_t*)ws; ws += NX * 2;
    f16_t* ctx  = (f16_t*)ws; ws += NX * 2;
    int*   flg  = (int*)ws;   ws += 64 * 4;

    prep_all<<<2048, 256, 0, stream>>>(x, mask, Wq, Wk, Wv, Wo,
                                       xf, wqkh, wqkl, wvf, wof, flg);

    dim3 gqkv(3 * DD / 128, (BB * SS) / 128);  // (24, 32) = 768 blocks
    gemm_qkv<<<gqkv, 256, 0, stream>>>(xf, wqkh, wqkl, wvf, bq, bk, bv, qf, kf, vt, DD);

    dim3 agrid(SS / 128, BH);  // (16, 32) = 512 blocks, 128 q-rows each, 8 waves
    attn_mfma13<<<agrid, 512, 0, stream>>>(qf, kf, vt, mask, flg, ctx, SS);

    dim3 go(DD / 128, (BB * SS) / 64);  // (8, 64) = 512 blocks
    gemm_o<<<go, 256, 0, stream>>>(ctx, wof, bo, out, DD, DD);
}

// Round 14
// 236.132 us; speedup vs baseline: 1.1760x; 1.0149x over previous
//
#include <hip/hip_runtime.h>
#include <hip/hip_bf16.h>
#include <math.h>

#define BB 2
#define SS 2048
#define DD 1024
#define HH 16
#define DKK 64
#define BH (BB * HH)          // 32

typedef __bf16 bf16_t;
typedef _Float16 f16_t;
typedef __attribute__((ext_vector_type(8))) _Float16 f16x8;
typedef __attribute__((ext_vector_type(4))) _Float16 f16x4;
typedef __attribute__((ext_vector_type(4))) float f32x4;
typedef __attribute__((ext_vector_type(4))) int i32x4;
typedef __attribute__((ext_vector_type(2))) int i32x2;

// async global->LDS, 16B per lane; lds base must be wave-uniform (lane*16 implicit)
#define GLD_LDS(gp, lp) __builtin_amdgcn_global_load_lds( \
    (const __attribute__((address_space(1))) void*)(gp),  \
    (__attribute__((address_space(3))) void*)(lp), 16, 0, 0)

static __device__ __forceinline__ int pkrtz(float a, float b) {
    auto h = __builtin_amdgcn_cvt_pkrtz(a, b);  // __fp16 ext_vector(2) on this clang
    return __builtin_bit_cast(int, h);
}

// ---------------------------------------------------------------- merged prep kernel
// Vectorized (G13): float4 loads, f16x4 stores. One launch for all casts + flags.
__global__ void prep_all(const float* __restrict__ x, const int* __restrict__ mask,
                         const float* __restrict__ Wq, const float* __restrict__ Wk,
                         const float* __restrict__ Wv, const float* __restrict__ Wo,
                         f16_t* __restrict__ xf,
                         f16_t* __restrict__ wqkh, f16_t* __restrict__ wqkl,
                         f16_t* __restrict__ wvf, f16_t* __restrict__ wof,
                         int* __restrict__ flags) {
    const int X4 = (BB * SS * DD) / 4;   // 1048576
    const int W4 = (DD * DD) / 4;        // 262144
    const int total = X4 + 4 * W4;       // 2097152
    int i = blockIdx.x * blockDim.x + threadIdx.x;
    const int stride = gridDim.x * blockDim.x;
    for (; i < total; i += stride) {
        if (i < X4) {
            f32x4 v = ((const f32x4*)x)[i];
            f16x4 h;
#pragma unroll
            for (int j = 0; j < 4; ++j) h[j] = (f16_t)v[j];
            ((f16x4*)xf)[i] = h;
        } else if (i < X4 + 2 * W4) {
            const int j = i - X4;
            f32x4 v = (j < W4) ? ((const f32x4*)Wq)[j] : ((const f32x4*)Wk)[j - W4];
            f16x4 h, l;
#pragma unroll
            for (int jj = 0; jj < 4; ++jj) {
                h[jj] = (f16_t)v[jj];
                l[jj] = (f16_t)(v[jj] - (float)h[jj]);
            }
            ((f16x4*)wqkh)[j] = h;
            ((f16x4*)wqkl)[j] = l;
        } else {
            int j = i - X4 - 2 * W4;
            if (j < W4) {
                f32x4 v = ((const f32x4*)Wv)[j];
                f16x4 h;
#pragma unroll
                for (int jj = 0; jj < 4; ++jj) h[jj] = (f16_t)v[jj];
                ((f16x4*)wvf)[j] = h;
            } else {
                j -= W4;
                f32x4 v = ((const f32x4*)Wo)[j];
                f16x4 h;
#pragma unroll
                for (int jj = 0; jj < 4; ++jj) h[jj] = (f16_t)v[jj];
                ((f16x4*)wof)[j] = h;
            }
        }
    }
    if (blockIdx.x == 0 && threadIdx.x < BB * (SS / 128)) {
        const int f = threadIdx.x;
        const int b = f / (SS / 128), t = f % (SS / 128);
        const int* p = mask + b * SS + t * 128;
        int all = 1;
        for (int j = 0; j < 128; ++j) all &= (p[j] != 0);
        flags[f] = all;
    }
}

// ---------------------------------------------------------------- fused QKV GEMM (fp16)
// BK=64, XOR-swizzled LDS: 16 K-steps, conflict-free ds_read_b128 (verified R12).
__global__ __launch_bounds__(256) void gemm_qkv(const f16_t* __restrict__ Af,
                                                const f16_t* __restrict__ Wqkh,
                                                const f16_t* __restrict__ Wqkl,
                                                const f16_t* __restrict__ Wvf,
                                                const float* __restrict__ bq,
                                                const float* __restrict__ bk,
                                                const float* __restrict__ bv,
                                                f16_t* __restrict__ q_o,
                                                f16_t* __restrict__ k_o,
                                                f16_t* __restrict__ vt_o,
                                                int K) {
    __shared__ __align__(16) f16_t sA[8192];   // 128 rows x 64 f16 (128B rows)
    __shared__ __align__(16) f16_t sB0[8192];
    __shared__ __align__(16) f16_t sB1[8192];

    const int tid  = threadIdx.x;
    const int wv   = tid >> 6;
    const int lane = tid & 63;
    const int quad = lane >> 4;
    const int l15  = lane & 15;
    const int wr   = wv >> 1;
    const int wc   = wv & 1;
    const int row0 = blockIdx.y * 128;
    const int col0 = blockIdx.x * 128;
    const bool isV = (col0 >= 2048);

    const f16_t* B0 = isV ? (Wvf + (long)(col0 - 2048) * K) : (Wqkh + (long)col0 * K);
    const f16_t* B1 = isV ? nullptr : (Wqkl + (long)col0 * K);

    f32x4 acc[4][4] = {};

    const int srow8 = lane >> 3;                   // row-within-8 (= row & 7)
    const int gsw   = ((lane & 7) ^ srow8) * 8;    // pre-swizzled global col
    const long aoff = (long)(row0 + wv * 8 + srow8) * K + gsw;
    const long boff = (long)(wv * 8 + srow8) * K + gsw;
    const int lsw   = l15 & 7;                     // read-side row&7

    if (isV) {
#pragma unroll 1
        for (int kb = 0; kb < K; kb += 64) {
#pragma unroll
            for (int p = 0; p < 4; ++p) {
                const long go = (long)p * 32 * K + kb;
                const int lo = p * 2048 + wv * 512;
                GLD_LDS(Af + aoff + go, sA + lo);
                GLD_LDS(B0 + boff + go, sB0 + lo);
            }
            __syncthreads();
#pragma unroll
            for (int kk = 0; kk < 2; ++kk) {
                f16x8 af[4];
#pragma unroll
                for (int mt = 0; mt < 4; ++mt)
                    af[mt] = *(const f16x8*)&sA[(wr * 64 + mt * 16 + l15) * 64 + (((kk * 4 + quad) ^ lsw) << 3)];
#pragma unroll
                for (int nt = 0; nt < 4; ++nt) {
                    f16x8 b0 = *(const f16x8*)&sB0[(wc * 64 + nt * 16 + l15) * 64 + (((kk * 4 + quad) ^ lsw) << 3)];
#pragma unroll
                    for (int mt = 0; mt < 4; ++mt)
                        acc[mt][nt] = __builtin_amdgcn_mfma_f32_16x16x32_f16(af[mt], b0, acc[mt][nt], 0, 0, 0);
                }
            }
            __syncthreads();
        }
    } else {
#pragma unroll 1
        for (int kb = 0; kb < K; kb += 64) {
#pragma unroll
            for (int p = 0; p < 4; ++p) {
                const long go = (long)p * 32 * K + kb;
                const int lo = p * 2048 + wv * 512;
                GLD_LDS(Af + aoff + go, sA + lo);
                GLD_LDS(B0 + boff + go, sB0 + lo);
                GLD_LDS(B1 + boff + go, sB1 + lo);
            }
            __syncthreads();
#pragma unroll
            for (int kk = 0; kk < 2; ++kk) {
                f16x8 af[4];
#pragma unroll
                for (int mt = 0; mt < 4; ++mt)
                    af[mt] = *(const f16x8*)&sA[(wr * 64 + mt * 16 + l15) * 64 + (((kk * 4 + quad) ^ lsw) << 3)];
#pragma unroll
                for (int nt = 0; nt < 4; ++nt) {
                    f16x8 b0 = *(const f16x8*)&sB0[(wc * 64 + nt * 16 + l15) * 64 + (((kk * 4 + quad) ^ lsw) << 3)];
                    f16x8 b1 = *(const f16x8*)&sB1[(wc * 64 + nt * 16 + l15) * 64 + (((kk * 4 + quad) ^ lsw) << 3)];
#pragma unroll
                    for (int mt = 0; mt < 4; ++mt) {
                        acc[mt][nt] = __builtin_amdgcn_mfma_f32_16x16x32_f16(af[mt], b0, acc[mt][nt], 0, 0, 0);
                        acc[mt][nt] = __builtin_amdgcn_mfma_f32_16x16x32_f16(af[mt], b1, acc[mt][nt], 0, 0, 0);
                    }
                }
            }
            __syncthreads();
        }
    }

    if (isV) {
#pragma unroll
        for (int nt = 0; nt < 4; ++nt) {
            const int colv = (col0 - 2048) + wc * 64 + nt * 16 + l15;  // [0,1024)
            const float bvv = bv[colv];
            const int hq = colv >> 6, dk = colv & 63;
#pragma unroll
            for (int mt = 0; mt < 4; ++mt) {
                const int grow0 = row0 + wr * 64 + mt * 16 + quad * 4;
                const int bq2 = grow0 >> 11;
                const int s0  = grow0 & (SS - 1);
                f16x4 pk;
#pragma unroll
                for (int r = 0; r < 4; ++r) pk[r] = (f16_t)(acc[mt][nt][r] + bvv);
                *(f16x4*)(vt_o + ((long)(bq2 * HH + hq) * DKK + dk) * SS + s0) = pk;
            }
        }
    } else {
        const bool isK = (col0 >= 1024);
        const float* bias = isK ? bk : bq;
        f16_t* op = isK ? k_o : q_o;
#pragma unroll
        for (int nt = 0; nt < 4; ++nt) {
            const int gcol = (col0 & 1023) + wc * 64 + nt * 16 + l15;
            const float bvv = bias[gcol];
            const int hq = gcol >> 6, dk = gcol & 63;
#pragma unroll
            for (int mt = 0; mt < 4; ++mt) {
                const int grow0 = row0 + wr * 64 + mt * 16 + quad * 4;
#pragma unroll
                for (int r = 0; r < 4; ++r) {
                    int grow = grow0 + r;
                    float vvv = acc[mt][nt][r] + bvv;
                    long off = (((long)(grow >> 11) * HH + hq) * SS + (grow & (SS - 1))) * DKK + dk;
                    op[off] = (f16_t)vvv;
                }
            }
        }
    }
}

// ---------------------------------------------------------------- O-projection GEMM (fp16 in, fp32 out)
// Tile 64x128, BK=64 + XOR swizzle (R12 recipe): 16 K-steps, conflict-free b128.
__global__ __launch_bounds__(256) void gemm_o(const f16_t* __restrict__ Ah,
                                              const f16_t* __restrict__ Bhp,
                                              const float* __restrict__ bias,
                                              float* __restrict__ outf,
                                              int N, int K) {
    __shared__ __align__(16) f16_t sA[4096];   // 64 rows x 64 f16
    __shared__ __align__(16) f16_t sB[8192];   // 128 rows x 64 f16

    const int tid  = threadIdx.x;
    const int wv   = tid >> 6;
    const int lane = tid & 63;
    const int quad = lane >> 4;
    const int l15  = lane & 15;
    const int wr   = wv >> 1;
    const int wc   = wv & 1;
    const int row0 = blockIdx.y * 64;
    const int col0 = blockIdx.x * 128;

    f32x4 acc[2][4] = {};

    const int srow8 = lane >> 3;
    const int gsw   = ((lane & 7) ^ srow8) * 8;
    const long aoff = (long)(row0 + wv * 8 + srow8) * K + gsw;
    const long boff = (long)(col0 + wv * 8 + srow8) * K + gsw;
    const int lsw   = l15 & 7;

#pragma unroll 1
    for (int kb = 0; kb < K; kb += 64) {
#pragma unroll
        for (int p = 0; p < 2; ++p) {   // A: 64 rows in 2 passes
            GLD_LDS(Ah + aoff + (long)p * 32 * K + kb, sA + p * 2048 + wv * 512);
        }
#pragma unroll
        for (int p = 0; p < 4; ++p) {   // B: 128 rows in 4 passes
            GLD_LDS(Bhp + boff + (long)p * 32 * K + kb, sB + p * 2048 + wv * 512);
        }
        __syncthreads();

#pragma unroll
        for (int kk = 0; kk < 2; ++kk) {
            f16x8 af[2];
#pragma unroll
            for (int mt = 0; mt < 2; ++mt)
                af[mt] = *(const f16x8*)&sA[(wr * 32 + mt * 16 + l15) * 64 + (((kk * 4 + quad) ^ lsw) << 3)];
#pragma unroll
            for (int nt = 0; nt < 4; ++nt) {
                f16x8 bh = *(const f16x8*)&sB[(wc * 64 + nt * 16 + l15) * 64 + (((kk * 4 + quad) ^ lsw) << 3)];
#pragma unroll
                for (int mt = 0; mt < 2; ++mt)
                    acc[mt][nt] = __builtin_amdgcn_mfma_f32_16x16x32_f16(af[mt], bh, acc[mt][nt], 0, 0, 0);
            }
        }
        __syncthreads();
    }

#pragma unroll
    for (int mt = 0; mt < 2; ++mt) {
#pragma unroll
        for (int nt = 0; nt < 4; ++nt) {
            const int gcol  = col0 + wc * 64 + nt * 16 + l15;
            const float bvv = bias[gcol];
            const int grow0 = row0 + wr * 32 + mt * 16 + quad * 4;
#pragma unroll
            for (int r = 0; r < 4; ++r)
                outf[(long)(grow0 + r) * N + gcol] = acc[mt][nt][r] + bvv;
        }
    }
}

// ---------------------------------------------------------------- MFMA flash attention v14
// v13 + 3-ary max tree (clang fuses nested fmaxf -> v_max3_f32, T17).
__global__ __launch_bounds__(512, 4) void attn_mfma14(const f16_t* __restrict__ Qp,
                                                      const f16_t* __restrict__ Kp,
                                                      const f16_t* __restrict__ Vtp,
                                                      const int* __restrict__ mask,
                                                      const int* __restrict__ flags,
                                                      f16_t* __restrict__ ctx,
                                                      int seq_len) {
    __shared__ __align__(16) f16_t Ksh[2][4096];      // single K tile, [64-key sub-tile][...]
    __shared__ __align__(16) f16_t Vsh[2][2][4096];   // dbuf V^T: [buf][sub-tile][d][key]

    const int tid  = threadIdx.x;
    const int wv   = tid >> 6;        // [0,8)
    const int lane = tid & 63;
    const int quad = lane >> 4;
    const int l15  = lane & 15;
    const int bh   = blockIdx.y;
    const int b    = bh >> 4;
    const int h    = bh & 15;
    const int q0   = blockIdx.x * 128 + wv * 16;

    const long kb = (long)bh * SS * DKK;

    f16x8 qf[2];
    {
        const f16_t* pq = Qp + kb + (long)(q0 + l15) * DKK + quad * 8;
        qf[0] = *(const f16x8*)pq;
        qf[1] = *(const f16x8*)(pq + 32);
        const f16_t qs = (f16_t)(8.0f * 1.44269504088896f);
#pragma unroll
        for (int j = 0; j < 8; ++j) { qf[0][j] *= qs; qf[1][j] *= qs; }
    }

    f16x4 ones4;
#pragma unroll
    for (int j = 0; j < 4; ++j) ones4[j] = (f16_t)1.0f;

    f32x4 o[4], lacc;
#pragma unroll
    for (int r = 0; r < 4; ++r) o[r] = (f32x4){0.f, 0.f, 0.f, 0.f};
    lacc = (f32x4){0.f, 0.f, 0.f, 0.f};
    float m = -1e30f;   // running max for q = l15

    const int* mrow = mask + b * SS;
    const int* frow = flags + b * (SS / 128);

    const int srow8 = lane >> 3;
    const int gcolB = ((lane & 7) ^ srow8) * 8;
    const int NT = seq_len >> 7;

    // prologue: stage K(0) -> Ksh, V(0) -> Vsh[0]; wave wv stages chunk wv per sub-tile
#pragma unroll
    for (int c = 0; c < 2; ++c) {
        const int row = wv * 8 + srow8;
        GLD_LDS(Kp + kb + (long)(c * 64 + row) * DKK + gcolB, &Ksh[c][wv * 512]);
        GLD_LDS(Vtp + kb + (long)row * SS + c * 64 + gcolB, &Vsh[0][c][wv * 512]);
    }

#pragma unroll 1
    for (int tt = 0; tt < NT; ++tt) {
        const int cur = tt & 1;
        const int kt = tt << 7;
        __syncthreads();   // B_top: K(tt) and V(tt)=Vsh[cur] staged (vmcnt drained)

        // QK^T swapped: s[nt][r] = S[key = (nt>>2)*64+(nt&3)*16+quad*4+r][q = l15]
        f32x4 s[8];
#pragma unroll
        for (int nt = 0; nt < 8; ++nt) s[nt] = (f32x4){0.f, 0.f, 0.f, 0.f};
#pragma unroll
        for (int nt = 0; nt < 8; ++nt) {
            const int c = nt >> 2;
            const int kr = (nt & 3) * 16 + l15;
#pragma unroll
            for (int dt = 0; dt < 2; ++dt) {
                f16x8 kf = *(const f16x8*)&Ksh[c][kr * 64 + (((dt * 4 + quad) ^ (l15 & 7)) << 3)];
                s[nt] = __builtin_amdgcn_mfma_f32_16x16x32_f16(kf, qf[dt], s[nt], 0, 0, 0);
            }
        }

        __syncthreads();   // B_mid: all waves done reading Ksh -> safe to restage
        if (tt + 1 < NT) {
            const int kn = (tt + 1) << 7;
#pragma unroll
            for (int c = 0; c < 2; ++c) {
                const int row = wv * 8 + srow8;
                GLD_LDS(Kp + kb + (long)(kn + c * 64 + row) * DKK + gcolB, &Ksh[c][wv * 512]);
                GLD_LDS(Vtp + kb + (long)row * SS + kn + c * 64 + gcolB, &Vsh[cur ^ 1][c][wv * 512]);
            }
        }

        if (!frow[kt >> 7]) {
#pragma unroll
            for (int nt = 0; nt < 8; ++nt) {
                i32x4 kp = *(const i32x4*)&mrow[kt + nt * 16 + quad * 4];
#pragma unroll
                for (int r = 0; r < 4; ++r)
                    s[nt][r] = kp[r] ? s[nt][r] : -1e30f;
            }
        }

        // max over this q-row's keys: 3-ary nests -> v_max3_f32 (4 insts/r vs 7)
        f32x4 mx;
#pragma unroll
        for (int r = 0; r < 4; ++r) {
            const float t1 = fmaxf(fmaxf(s[0][r], s[1][r]), s[2][r]);
            const float t2 = fmaxf(fmaxf(s[3][r], s[4][r]), s[5][r]);
            const float t3 = fmaxf(fmaxf(s[6][r], s[7][r]), t1);
            mx[r] = fmaxf(t2, t3);
        }
        float tm = fmaxf(fmaxf(fmaxf(mx[0], mx[1]), mx[2]), mx[3]);
        tm = fmaxf(tm, __shfl_xor(tm, 16));
        tm = fmaxf(tm, __shfl_xor(tm, 32));

        // defer-max: only rescale when the max grew by > 8 (log2 domain)
        if (__any(tm > m + 8.0f)) {
            const float mn = fmaxf(m, tm);
            const float alpha = exp2f(m - mn);
            float a4[4];
#pragma unroll
            for (int r = 0; r < 4; ++r) a4[r] = __shfl(alpha, quad * 4 + r);
#pragma unroll
            for (int t = 0; t < 4; ++t)
#pragma unroll
                for (int r = 0; r < 4; ++r) o[t][r] *= a4[r];
#pragma unroll
            for (int r = 0; r < 4; ++r) lacc[r] *= a4[r];
            m = mn;
        }

        // per 16-key group: exp -> pack -> rowsum MFMA + PV MFMAs
#pragma unroll
        for (int nt = 0; nt < 8; ++nt) {
            const int c = nt >> 2;
            i32x2 pp;
            pp[0] = pkrtz(exp2f(s[nt][0] - m), exp2f(s[nt][1] - m));
            pp[1] = pkrtz(exp2f(s[nt][2] - m), exp2f(s[nt][3] - m));
            f16x4 paf = __builtin_bit_cast(f16x4, pp);
            lacc = __builtin_amdgcn_mfma_f32_16x16x16f16(paf, ones4, lacc, 0, 0, 0);
            const int vcol = ((((nt & 3) * 2 + (quad >> 1)) ^ (l15 & 7)) << 3) + ((quad & 1) << 2);
#pragma unroll
            for (int t = 0; t < 4; ++t) {
                f16x4 vB = *(const f16x4*)&Vsh[cur][c][(t * 16 + l15) * 64 + vcol];
                o[t] = __builtin_amdgcn_mfma_f32_16x16x16f16(paf, vB, o[t], 0, 0, 0);
            }
        }
    }

    float inv[4];
#pragma unroll
    for (int r = 0; r < 4; ++r) inv[r] = 1.0f / lacc[r];
#pragma unroll
    for (int t = 0; t < 4; ++t) {
        int d = t * 16 + l15;
#pragma unroll
        for (int r = 0; r < 4; ++r) {
            int tok = b * SS + q0 + quad * 4 + r;
            ctx[(long)tok * DD + h * DKK + d] = (f16_t)(o[t][r] * inv[r]);
        }
    }
}

// ---------------------------------------------------------------- launch
extern "C" void kernel_launch(void* const* d_in, const int* in_sizes, int n_in,
                              void* d_out, int out_size, void* d_ws, size_t ws_size,
                              hipStream_t stream) {
    const float* x  = (const float*)d_in[0];
    const int* mask = (const int*)d_in[1];
    const float* Wq = (const float*)d_in[2];
    const float* bq = (const float*)d_in[3];
    const float* Wk = (const float*)d_in[4];
    const float* bk = (const float*)d_in[5];
    const float* Wv = (const float*)d_in[6];
    const float* bv = (const float*)d_in[7];
    const float* Wo = (const float*)d_in[8];
    const float* bo = (const float*)d_in[9];
    float* out = (float*)d_out;

    const long NX = (long)BB * SS * DD;  // 4194304
    const long NW = (long)DD * DD;       // 1048576

    char* ws = (char*)d_ws;
    f16_t* xf   = (f16_t*)ws; ws += NX * 2;
    f16_t* wqkh = (f16_t*)ws; ws += 2 * NW * 2;
    f16_t* wqkl = (f16_t*)ws; ws += 2 * NW * 2;
    f16_t* wvf  = (f16_t*)ws; ws += NW * 2;
    f16_t* wof  = (f16_t*)ws; ws += NW * 2;
    f16_t* qf   = (f16_t*)ws; ws += NX * 2;
    f16_t* kf   = (f16_t*)ws; ws += NX * 2;
    f16_t* vt   = (f16_t*)ws; ws += NX * 2;
    f16_t* ctx  = (f16_t*)ws; ws += NX * 2;
    int*   flg  = (int*)ws;   ws += 64 * 4;

    prep_all<<<2048, 256, 0, stream>>>(x, mask, Wq, Wk, Wv, Wo,
                                       xf, wqkh, wqkl, wvf, wof, flg);

    dim3 gqkv(3 * DD / 128, (BB * SS) / 128);  // (24, 32) = 768 blocks
    gemm_qkv<<<gqkv, 256, 0, stream>>>(xf, wqkh, wqkl, wvf, bq, bk, bv, qf, kf, vt, DD);

    dim3 agrid(SS / 128, BH);  // (16, 32) = 512 blocks, 128 q-rows each, 8 waves
    attn_mfma14<<<agrid, 512, 0, stream>>>(qf, kf, vt, mask, flg, ctx, SS);

    dim3 go(DD / 128, (BB * SS) / 64);  // (8, 64) = 512 blocks
    gemm_o<<<go, 256, 0, stream>>>(ctx, wof, bo, out, DD, DD);
}